// Round 1
// 1048.642 us; speedup vs baseline: 1.3723x; 1.3723x over previous
//
#include <hip/hip_runtime.h>
#include <stdint.h>

// ---------------------------------------------------------------------------
// HGP-SL GNN forward on MI355X.  Round 7.
//  - gemm_xw -> split-bf16 MFMA (3-term: hi*hi + hi*lo + lo*hi), ~fp32 accurate.
//    W1 pre-split+transposed to bf16 [N][K] (L2-resident, B frags from global).
//  - aggregate: single launch; h written straight to OUT x__ region (no XW/H
//    aliasing -> no 16-launch stagger). XCD-chunked block swizzle for L2.
//  - readouts: (B,4)-chunked partials + atomicMax(uint)/atomicAdd (inputs >=0).
// Workspace map (MB):
//  [0,64)    XW ; after XW dead: ADJ1 [0,32), X2 [32,64); then X3 [32,48), H3 [48,64)
//  [68,72)   CSR   [72,73) degree arrays   [73,73.25) SCORE
//  [76,108)  H1 -> reused as H2
//  [108,116) ADJ2
//  [116,~118.7) persistent misc (incl. Whi/Wlo bf16 splits)
// ---------------------------------------------------------------------------

#define B_   128
#define N_   512
#define NN_  65536
#define E_   1048576
#define LAMB_ 1.0f

typedef unsigned short ushort_t;
typedef __attribute__((ext_vector_type(8))) short bf16x8;
typedef __attribute__((ext_vector_type(8))) unsigned short u16x8;
typedef __attribute__((ext_vector_type(4))) float f32x4;

__device__ inline float waveReduceSum(float v) {
    #pragma unroll
    for (int o = 32; o > 0; o >>= 1) v += __shfl_down(v, o, 64);
    return v;
}

__device__ inline ushort_t f2bf(float f) {
    unsigned u = __float_as_uint(f);
    u += 0x7fffu + ((u >> 16) & 1u);
    return (ushort_t)(u >> 16);
}

// ---------------- 1a. W1 split+transpose: W[512][256] -> Whi/Wlo [256][512] -
__global__ void split_w_kernel(const float* __restrict__ W, ushort_t* __restrict__ Whi,
                               ushort_t* __restrict__ Wlo) {
    int k = blockIdx.x;    // 512
    int n = threadIdx.x;   // 256
    float w = W[k * 256 + n];
    ushort_t h = f2bf(w);
    float hf = __uint_as_float((unsigned)h << 16);
    ushort_t l = f2bf(w - hf);
    Whi[n * 512 + k] = h;
    Wlo[n * 512 + k] = l;
}

// ---------------- 1b. split-bf16 MFMA GEMM: XW = x @ W1 (65536x512 @ 512x256)
// 128x128 tile, 4 waves of 64x64, BK=32, mfma_f32_16x16x32_bf16.
__global__ __launch_bounds__(256) void gemm_xw_mfma(
    const float* __restrict__ A, const ushort_t* __restrict__ Bhi,
    const ushort_t* __restrict__ Blo, float* __restrict__ C) {
    int m0 = blockIdx.x * 128, n0 = blockIdx.y * 128;
    __shared__ __align__(16) ushort_t As[2][4][128][8];  // [hi/lo][khi][m][j] 16KB
    int tid = threadIdx.x;
    int lane = tid & 63, w = tid >> 6;
    int wm = (w & 1) * 64, wn = (w >> 1) * 64;
    int fl = lane & 15, fh = lane >> 4;
    f32x4 acc[4][4] = {};
    int sm = tid >> 1, sk = (tid & 1) * 16;
    const float* Ap = A + (size_t)(m0 + sm) * 512 + sk;
    float4 p0 = *(const float4*)(Ap + 0);
    float4 p1 = *(const float4*)(Ap + 4);
    float4 p2 = *(const float4*)(Ap + 8);
    float4 p3 = *(const float4*)(Ap + 12);
    for (int ks = 0; ks < 16; ks++) {
        float f0[8] = {p0.x, p0.y, p0.z, p0.w, p1.x, p1.y, p1.z, p1.w};
        float f1[8] = {p2.x, p2.y, p2.z, p2.w, p3.x, p3.y, p3.z, p3.w};
        u16x8 h0, h1, l0, l1;
        #pragma unroll
        for (int i = 0; i < 8; i++) {
            unsigned u = __float_as_uint(f0[i]);
            unsigned rh = u + 0x7fffu + ((u >> 16) & 1u);
            ushort_t hh = (ushort_t)(rh >> 16);
            float lf = f0[i] - __uint_as_float((unsigned)hh << 16);
            unsigned ul = __float_as_uint(lf);
            unsigned rl = ul + 0x7fffu + ((ul >> 16) & 1u);
            h0[i] = hh;
            l0[i] = (ushort_t)(rl >> 16);
        }
        #pragma unroll
        for (int i = 0; i < 8; i++) {
            unsigned u = __float_as_uint(f1[i]);
            unsigned rh = u + 0x7fffu + ((u >> 16) & 1u);
            ushort_t hh = (ushort_t)(rh >> 16);
            float lf = f1[i] - __uint_as_float((unsigned)hh << 16);
            unsigned ul = __float_as_uint(lf);
            unsigned rl = ul + 0x7fffu + ((ul >> 16) & 1u);
            h1[i] = hh;
            l1[i] = (ushort_t)(rl >> 16);
        }
        __syncthreads();  // protect previous iter's As reads
        int khi = sk >> 3;
        *(u16x8*)&As[0][khi][sm][0]     = h0;
        *(u16x8*)&As[0][khi + 1][sm][0] = h1;
        *(u16x8*)&As[1][khi][sm][0]     = l0;
        *(u16x8*)&As[1][khi + 1][sm][0] = l1;
        __syncthreads();
        if (ks < 15) {  // prefetch next K-step before MFMA block
            Ap += 32;
            p0 = *(const float4*)(Ap + 0);
            p1 = *(const float4*)(Ap + 4);
            p2 = *(const float4*)(Ap + 8);
            p3 = *(const float4*)(Ap + 12);
        }
        bf16x8 ah[4], al[4], bh[4], bl[4];
        #pragma unroll
        for (int mi = 0; mi < 4; mi++) {
            ah[mi] = *(const bf16x8*)&As[0][fh][wm + mi * 16 + fl][0];
            al[mi] = *(const bf16x8*)&As[1][fh][wm + mi * 16 + fl][0];
        }
        int kg = ks * 32 + fh * 8;
        #pragma unroll
        for (int ni = 0; ni < 4; ni++) {
            size_t boff = (size_t)(n0 + wn + ni * 16 + fl) * 512 + kg;
            bh[ni] = *(const bf16x8*)&Bhi[boff];
            bl[ni] = *(const bf16x8*)&Blo[boff];
        }
        #pragma unroll
        for (int mi = 0; mi < 4; mi++)
            #pragma unroll
            for (int ni = 0; ni < 4; ni++) {
                acc[mi][ni] = __builtin_amdgcn_mfma_f32_16x16x32_bf16(al[mi], bh[ni], acc[mi][ni], 0, 0, 0);
                acc[mi][ni] = __builtin_amdgcn_mfma_f32_16x16x32_bf16(ah[mi], bl[ni], acc[mi][ni], 0, 0, 0);
                acc[mi][ni] = __builtin_amdgcn_mfma_f32_16x16x32_bf16(ah[mi], bh[ni], acc[mi][ni], 0, 0, 0);
            }
    }
    #pragma unroll
    for (int mi = 0; mi < 4; mi++)
        #pragma unroll
        for (int ni = 0; ni < 4; ni++)
            #pragma unroll
            for (int r = 0; r < 4; r++)
                C[(size_t)(m0 + wm + mi * 16 + fh * 4 + r) * 256 + n0 + wn + ni * 16 + fl]
                    = acc[mi][ni][r];
}

// ---------------- 2. CSR build ----------------------------------------------
__global__ void count_kernel(const int* __restrict__ dst, int* __restrict__ indeg) {
    int e = blockIdx.x * 256 + threadIdx.x;
    if (e < E_) atomicAdd(&indeg[dst[e] & 65535], 1);
}
__global__ void scan_kernel(const int* __restrict__ indeg, int* __restrict__ rowstart,
                            int* __restrict__ cursor) {
    __shared__ int part[1024];
    int t = threadIdx.x;
    int base = t * 64;
    int s = 0;
    for (int i = 0; i < 64; i++) s += indeg[base + i];
    part[t] = s;
    __syncthreads();
    for (int off = 1; off < 1024; off <<= 1) {
        int v = (t >= off) ? part[t - off] : 0;
        __syncthreads();
        part[t] += v;
        __syncthreads();
    }
    int run = (t == 0) ? 0 : part[t - 1];
    for (int i = 0; i < 64; i++) {
        rowstart[base + i] = run;
        cursor[base + i] = run;
        run += indeg[base + i];
    }
}
__global__ void scatter_csr_kernel(const int* __restrict__ src, const int* __restrict__ dst,
                                   int* __restrict__ cursor, int* __restrict__ csr) {
    int e = blockIdx.x * 256 + threadIdx.x;
    if (e < E_) {
        int pos = atomicAdd(&cursor[dst[e] & 65535], 1);
        csr[pos & (E_ - 1)] = src[e] & 65535;
    }
}
__global__ void dinv_kernel(const int* __restrict__ indeg, float* __restrict__ dinv) {
    int i = blockIdx.x * 256 + threadIdx.x;
    dinv[i] = rsqrtf((float)indeg[i] + 1.0f);
}

// ---------------- 3. sparse GCN aggregate (single launch, h -> OUT x__) -----
__global__ void aggregate_kernel(const float4* __restrict__ xw, const int* __restrict__ rowstart,
                                 const int* __restrict__ indeg, const float* __restrict__ dinv,
                                 const int* __restrict__ csr, const float* __restrict__ b1,
                                 float4* __restrict__ hout) {
    int bid = (blockIdx.x & 7) * 2048 + (blockIdx.x >> 3);  // XCD-chunked swizzle (16384 % 8 == 0)
    int node = bid * 4 + (threadIdx.x >> 6);
    int lane = threadIdx.x & 63;
    int beg = rowstart[node], cnt = indeg[node];
    float di = dinv[node];
    float4 acc = make_float4(0.f, 0.f, 0.f, 0.f);
    for (int t = 0; t < cnt; t++) {
        int s = csr[(beg + t) & (E_ - 1)] & 65535;
        float w = dinv[s] * di;
        float4 v = xw[(size_t)s * 64 + lane];
        acc.x += v.x * w; acc.y += v.y * w; acc.z += v.z * w; acc.w += v.w * w;
    }
    {
        float w = di * di;
        float4 v = xw[(size_t)node * 64 + lane];
        acc.x += v.x * w; acc.y += v.y * w; acc.z += v.z * w; acc.w += v.w * w;
    }
    int c4 = lane * 4;
    acc.x = fmaxf(acc.x + b1[c4 + 0], 0.f);
    acc.y = fmaxf(acc.y + b1[c4 + 1], 0.f);
    acc.z = fmaxf(acc.z + b1[c4 + 2], 0.f);
    acc.w = fmaxf(acc.w + b1[c4 + 3], 0.f);
    hout[(size_t)node * 64 + lane] = acc;   // h == x__ output, f32
}

// ---------------- 4. pool_sparse score --------------------------------------
__global__ void score_kernel(const float4* __restrict__ h, const int* __restrict__ rowstart,
                             const int* __restrict__ indeg, const int* __restrict__ csr,
                             float* __restrict__ score) {
    int bid = (blockIdx.x & 7) * 2048 + (blockIdx.x >> 3);
    int node = bid * 4 + (threadIdx.x >> 6);
    int lane = threadIdx.x & 63;
    int beg = rowstart[node], cnt = indeg[node];
    float degp = fmaxf((float)cnt, 1.0f);
    float4 nb = make_float4(0.f, 0.f, 0.f, 0.f);
    for (int t = 0; t < cnt; t++) {
        int s = csr[(beg + t) & (E_ - 1)] & 65535;
        float4 v = h[(size_t)s * 64 + lane];
        nb.x += v.x; nb.y += v.y; nb.z += v.z; nb.w += v.w;
    }
    float4 x = h[(size_t)node * 64 + lane];
    float p = fabsf(x.x - nb.x / degp) + fabsf(x.y - nb.y / degp) +
              fabsf(x.z - nb.z / degp) + fabsf(x.w - nb.w / degp);
    p = waveReduceSum(p);
    if (lane == 0) score[node] = p;
}

// ---------------- 5. bitonic top-k (full sort, descending, tie->lower idx) --
__global__ void topk_kernel(const float* __restrict__ score, int n, int k,
                            int* __restrict__ out_local, int* __restrict__ rank, int Nfull) {
    int b = blockIdx.x, i = threadIdx.x;
    __shared__ float ss[512];
    __shared__ int si[512];
    ss[i] = score[b * n + i];
    si[i] = i;
    __syncthreads();
    for (int kk = 2; kk <= n; kk <<= 1)
        for (int j = kk >> 1; j > 0; j >>= 1) {
            int l = i ^ j;
            if (l > i) {
                float s1 = ss[i], s2 = ss[l];
                int i1 = si[i], i2 = si[l];
                bool up = ((i & kk) == 0);
                bool before = (s1 > s2) || (s1 == s2 && i1 < i2);
                bool doswap = up ? (!before) : before;
                if (doswap) { ss[i] = s2; ss[l] = s1; si[i] = i2; si[l] = i1; }
            }
            __syncthreads();
        }
    if (i < k) {
        int loc = si[i];
        out_local[b * k + i] = loc;
        if (rank) rank[b * Nfull + loc] = i;
    }
}

// ---------------- gathers / readouts / e-f dots -----------------------------
__global__ void gather_rows_kernel(const float4* __restrict__ src, const int* __restrict__ idxl,
                                   int k, int Nfull, float4* __restrict__ dstp) {
    int row = blockIdx.x;
    int b = row / k;
    int node = b * Nfull + (idxl[row] & (Nfull - 1));
    dstp[(size_t)row * 64 + threadIdx.x] = src[(size_t)node * 64 + threadIdx.x];
}
// chunked readout; inputs are post-relu (>=0) so uint atomicMax is order-preserving.
// out must be zeroed first. mean partials pre-scaled by 1/k.
__global__ void readout_kernel(const float* __restrict__ x, int k, float* __restrict__ out) {
    int b = blockIdx.x, q = blockIdx.y, c = threadIdx.x;
    int chunk = k >> 2;
    int j0 = q * chunk;
    float mx = 0.f, sm = 0.f;
    for (int j = j0; j < j0 + chunk; j++) {
        float v = x[((size_t)(b * k + j)) * 256 + c];
        mx = fmaxf(mx, v);
        sm += v;
    }
    atomicMax((unsigned int*)&out[b * 512 + c], __float_as_uint(mx));
    atomicAdd(&out[b * 512 + 256 + c], sm * (1.0f / (float)k));
}
__global__ void readout_idx_kernel(const float* __restrict__ x, const int* __restrict__ idx,
                                   int k, int Nfull, float* __restrict__ out) {
    int b = blockIdx.x, q = blockIdx.y, c = threadIdx.x;
    int chunk = k >> 2;
    int j0 = q * chunk;
    float mx = 0.f, sm = 0.f;
    for (int j = j0; j < j0 + chunk; j++) {
        int node = b * Nfull + (idx[b * k + j] & (Nfull - 1));
        float v = x[(size_t)node * 256 + c];
        mx = fmaxf(mx, v);
        sm += v;
    }
    atomicMax((unsigned int*)&out[b * 512 + c], __float_as_uint(mx));
    atomicAdd(&out[b * 512 + 256 + c], sm * (1.0f / (float)k));
}
__global__ void ef_plain_kernel(const float4* __restrict__ x, const float* __restrict__ att,
                                float* __restrict__ e, float* __restrict__ f) {
    int row = blockIdx.x * 4 + (threadIdx.x >> 6);
    int lane = threadIdx.x & 63;
    float4 v = x[(size_t)row * 64 + lane];
    const float* ap = att + lane * 8;
    float es = v.x * ap[0] + v.y * ap[2] + v.z * ap[4] + v.w * ap[6];
    float fs = v.x * ap[1] + v.y * ap[3] + v.z * ap[5] + v.w * ap[7];
    es = waveReduceSum(es);
    fs = waveReduceSum(fs);
    if (lane == 0) { e[row] = es; f[row] = fs; }
}
__global__ void ef_idx_kernel(const float4* __restrict__ x, const int* __restrict__ idx,
                              int k, int Nfull, const float* __restrict__ att,
                              float* __restrict__ e, float* __restrict__ f) {
    int row = blockIdx.x * 4 + (threadIdx.x >> 6);
    int lane = threadIdx.x & 63;
    int b = row / k;
    int node = b * Nfull + (idx[row] & (Nfull - 1));
    float4 v = x[(size_t)node * 64 + lane];
    const float* ap = att + lane * 8;
    float es = v.x * ap[0] + v.y * ap[2] + v.z * ap[4] + v.w * ap[6];
    float fs = v.x * ap[1] + v.y * ap[3] + v.z * ap[5] + v.w * ap[7];
    es = waveReduceSum(es);
    fs = waveReduceSum(fs);
    if (lane == 0) { e[row] = es; f[row] = fs; }
}

// ---------------- A_ind scatter & softmax & rowsums -------------------------
__global__ void scatter_A_kernel(const int* __restrict__ src, const int* __restrict__ dst,
                                 const int* __restrict__ rank, float* __restrict__ adj1) {
    int e = blockIdx.x * 256 + threadIdx.x;
    if (e >= E_) return;
    int s = src[e] & 65535, d = dst[e] & 65535;
    int ns = rank[s], nd = rank[d];
    if ((unsigned)ns < 256u && (unsigned)nd < 256u) {
        int g = s >> 9;
        adj1[(size_t)g * 65536 + ns * 256 + nd] = 1.0f;
    }
}
__global__ void softmax_adj_kernel(float* __restrict__ adj, const float* __restrict__ e,
                                   const float* __restrict__ f, int k) {
    int row = blockIdx.x;
    int b = row / k;
    int c = threadIdx.x;
    __shared__ float red[256];
    float v = adj[(size_t)row * k + c];
    float lg = e[row] + f[b * k + c] + LAMB_ * v;
    red[c] = lg;
    __syncthreads();
    for (int s = k >> 1; s > 0; s >>= 1) {
        if (c < s) red[c] = fmaxf(red[c], red[c + s]);
        __syncthreads();
    }
    float mx = red[0];
    __syncthreads();
    float ex = expf(lg - mx);
    red[c] = ex;
    __syncthreads();
    for (int s = k >> 1; s > 0; s >>= 1) {
        if (c < s) red[c] += red[c + s];
        __syncthreads();
    }
    adj[(size_t)row * k + c] = ex / red[0];
}
__global__ void rowsum_kernel(const float* __restrict__ adj, int k,
                              float* __restrict__ rowsum, float* __restrict__ dinv) {
    int row = blockIdx.x * 4 + (threadIdx.x >> 6);
    int lane = threadIdx.x & 63;
    float s = 0.f;
    for (int c = lane; c < k; c += 64) s += adj[(size_t)row * k + c];
    s = waveReduceSum(s);
    if (lane == 0) { rowsum[row] = s; dinv[row] = rsqrtf(s + 1.0f); }
}
__global__ void gather_adj2_kernel(const float* __restrict__ adj1, const int* __restrict__ idx2,
                                   float* __restrict__ adj2) {
    int ii = blockIdx.x, b = blockIdx.y, jj = threadIdx.x;
    int ri = idx2[b * 128 + ii] & 255, rj = idx2[b * 128 + jj] & 255;
    adj2[((size_t)(b * 128 + ii)) * 128 + jj] = adj1[(size_t)b * 65536 + ri * 256 + rj];
}
__global__ void bn_kernel(const float* g, const float* be,
                          const float* me, const float* va,
                          float* sBN, float* tBN) {
    int c = threadIdx.x;
    float s = g[c] * rsqrtf(va[c] + 1e-5f);
    sBN[c] = s;
    tBN[c] = be[c] - me[c] * s;
}

// ---------------- SIMT fp32 tiled GEMMs (64x64 tile, BK=16) -----------------
#define GEMM_PROLOG \
    int b = blockIdx.z; \
    int m0 = blockIdx.x * 64, n0 = blockIdx.y * 64; \
    __shared__ float As[16 * 68], Bs[16 * 68]; \
    int tid = threadIdx.x, tx = tid & 15, ty = tid >> 4; \
    float acc[4][4] = {{0.f}}; \
    (void)b;

#define GEMM_INNER \
    __syncthreads(); \
    _Pragma("unroll") \
    for (int kk = 0; kk < 16; kk++) { \
        float4 a = *(const float4*)&As[kk * 68 + ty * 4]; \
        float4 bv = *(const float4*)&Bs[kk * 68 + tx * 4]; \
        float av[4] = {a.x, a.y, a.z, a.w}; \
        float bb[4] = {bv.x, bv.y, bv.z, bv.w}; \
        _Pragma("unroll") \
        for (int i2 = 0; i2 < 4; i2++) \
            _Pragma("unroll") \
            for (int j2 = 0; j2 < 4; j2++) acc[i2][j2] += av[i2] * bb[j2]; \
    }

// (a) X2 = dinv1_row * (BN(H1) @ W2)
__global__ __launch_bounds__(256) void gemm_x2_kernel(
    const float* __restrict__ H1, const float* __restrict__ W2,
    const float* __restrict__ sBN, const float* __restrict__ tBN,
    const float* __restrict__ dinv1, float* __restrict__ X2) {
    GEMM_PROLOG
    const float* A = H1 + (size_t)b * 65536;
    for (int k0 = 0; k0 < 256; k0 += 16) {
        __syncthreads();
        #pragma unroll
        for (int i = 0; i < 4; i++) {
            int idx = tid + i * 256;
            int kk = idx & 15, m = idx >> 4;
            As[kk * 68 + m] = A[(m0 + m) * 256 + k0 + kk] * sBN[k0 + kk] + tBN[k0 + kk];
        }
        #pragma unroll
        for (int i = 0; i < 4; i++) {
            int idx = tid + i * 256;
            int n = idx & 63, kk = idx >> 6;
            Bs[kk * 68 + n] = W2[(k0 + kk) * 256 + n0 + n];
        }
        GEMM_INNER
    }
    #pragma unroll
    for (int i = 0; i < 4; i++) {
        int row = m0 + ty * 4 + i;
        float dv = dinv1[b * 256 + row];
        #pragma unroll
        for (int j = 0; j < 4; j++)
            X2[(size_t)b * 65536 + row * 256 + n0 + tx * 4 + j] = acc[i][j] * dv;
    }
}

// (b) H2 = relu(dinv1_i*(ADJ1@X2 + X2_i) + b2)
__global__ __launch_bounds__(256) void gemm_h2_kernel(
    const float* __restrict__ ADJ1, const float* __restrict__ X2,
    const float* __restrict__ dinv1, const float* __restrict__ b2,
    float* __restrict__ H2) {
    GEMM_PROLOG
    const float* A = ADJ1 + (size_t)b * 65536;
    const float* Bp = X2 + (size_t)b * 65536;
    for (int k0 = 0; k0 < 256; k0 += 16) {
        __syncthreads();
        #pragma unroll
        for (int i = 0; i < 4; i++) {
            int idx = tid + i * 256;
            int kk = idx & 15, m = idx >> 4;
            As[kk * 68 + m] = A[(m0 + m) * 256 + k0 + kk];
        }
        #pragma unroll
        for (int i = 0; i < 4; i++) {
            int idx = tid + i * 256;
            int n = idx & 63, kk = idx >> 6;
            Bs[kk * 68 + n] = Bp[(k0 + kk) * 256 + n0 + n];
        }
        GEMM_INNER
    }
    #pragma unroll
    for (int i = 0; i < 4; i++) {
        int row = m0 + ty * 4 + i;
        float dv = dinv1[b * 256 + row];
        #pragma unroll
        for (int j = 0; j < 4; j++) {
            int col = n0 + tx * 4 + j;
            float v = (acc[i][j] + X2[(size_t)b * 65536 + row * 256 + col]) * dv + b2[col];
            H2[(size_t)b * 65536 + row * 256 + col] = fmaxf(v, 0.f);
        }
    }
}

// (c) score2 += sum_cols |H2 - (ADJ1@H2)/deg|
__global__ __launch_bounds__(256) void gemm_score_kernel(
    const float* __restrict__ ADJ1, const float* __restrict__ H2,
    const float* __restrict__ rowsum1, float* __restrict__ score2) {
    GEMM_PROLOG
    const float* A = ADJ1 + (size_t)b * 65536;
    const float* Bp = H2 + (size_t)b * 65536;
    for (int k0 = 0; k0 < 256; k0 += 16) {
        __syncthreads();
        #pragma unroll
        for (int i = 0; i < 4; i++) {
            int idx = tid + i * 256;
            int kk = idx & 15, m = idx >> 4;
            As[kk * 68 + m] = A[(m0 + m) * 256 + k0 + kk];
        }
        #pragma unroll
        for (int i = 0; i < 4; i++) {
            int idx = tid + i * 256;
            int n = idx & 63, kk = idx >> 6;
            Bs[kk * 68 + n] = Bp[(k0 + kk) * 256 + n0 + n];
        }
        GEMM_INNER
    }
    float rpart[4];
    #pragma unroll
    for (int i = 0; i < 4; i++) {
        int row = m0 + ty * 4 + i;
        float deg = fmaxf(rowsum1[b * 256 + row], 1e-9f);
        float s = 0.f;
        #pragma unroll
        for (int j = 0; j < 4; j++) {
            int col = n0 + tx * 4 + j;
            s += fabsf(H2[(size_t)b * 65536 + row * 256 + col] - acc[i][j] / deg);
        }
        rpart[i] = s;
    }
    __syncthreads();
    #pragma unroll
    for (int i = 0; i < 4; i++) As[(ty * 4 + i) * 17 + tx] = rpart[i];
    __syncthreads();
    if (tid < 64) {
        float s = 0.f;
        #pragma unroll
        for (int x = 0; x < 16; x++) s += As[tid * 17 + x];
        atomicAdd(&score2[b * 256 + m0 + tid], s);
    }
}

// (d) X3[sel] = dinv2_sel * (H2[idx2[sel]] @ W3)
__global__ __launch_bounds__(256) void gemm_x3_kernel(
    const float* __restrict__ H2, const int* __restrict__ idx2,
    const float* __restrict__ W3,
    const float* __restrict__ dinv2, float* __restrict__ X3) {
    GEMM_PROLOG
    __shared__ int rowsS[64];
    if (tid < 64) rowsS[tid] = b * 256 + (idx2[b * 128 + m0 + tid] & 255);
    for (int k0 = 0; k0 < 256; k0 += 16) {
        __syncthreads();
        #pragma unroll
        for (int i = 0; i < 4; i++) {
            int idx = tid + i * 256;
            int kk = idx & 15, m = idx >> 4;
            As[kk * 68 + m] = H2[(size_t)rowsS[m] * 256 + k0 + kk];
        }
        #pragma unroll
        for (int i = 0; i < 4; i++) {
            int idx = tid + i * 256;
            int n = idx & 63, kk = idx >> 6;
            Bs[kk * 68 + n] = W3[(k0 + kk) * 256 + n0 + n];
        }
        GEMM_INNER
    }
    #pragma unroll
    for (int i = 0; i < 4; i++) {
        int row = m0 + ty * 4 + i;
        float dv = dinv2[b * 128 + row];
        #pragma unroll
        for (int j = 0; j < 4; j++)
            X3[(size_t)b * 32768 + row * 256 + n0 + tx * 4 + j] = acc[i][j] * dv;
    }
}

// (e) H3 = relu(dinv2_i*(ADJ2@X3 + X3_i) + b3), K=128
__global__ __launch_bounds__(256) void gemm_h3_kernel(
    const float* __restrict__ ADJ2, const float* __restrict__ X3,
    const float* __restrict__ dinv2, const float* __restrict__ b3,
    float* __restrict__ H3) {
    GEMM_PROLOG
    const float* A = ADJ2 + (size_t)b * 16384;
    const float* Bp = X3 + (size_t)b * 32768;
    for (int k0 = 0; k0 < 128; k0 += 16) {
        __syncthreads();
        #pragma unroll
        for (int i = 0; i < 4; i++) {
            int idx = tid + i * 256;
            int kk = idx & 15, m = idx >> 4;
            As[kk * 68 + m] = A[(m0 + m) * 128 + k0 + kk];
        }
        #pragma unroll
        for (int i = 0; i < 4; i++) {
            int idx = tid + i * 256;
            int n = idx & 63, kk = idx >> 6;
            Bs[kk * 68 + n] = Bp[(k0 + kk) * 256 + n0 + n];
        }
        GEMM_INNER
    }
    #pragma unroll
    for (int i = 0; i < 4; i++) {
        int row = m0 + ty * 4 + i;
        float dv = dinv2[b * 128 + row];
        #pragma unroll
        for (int j = 0; j < 4; j++) {
            int col = n0 + tx * 4 + j;
            float v = (acc[i][j] + X3[(size_t)b * 32768 + row * 256 + col]) * dv + b3[col];
            H3[(size_t)b * 32768 + row * 256 + col] = fmaxf(v, 0.f);
        }
    }
}

// ---------------- head MLP (f32 outputs) ------------------------------------
__global__ void head_kernel(const float* __restrict__ x1, const float* __restrict__ x2,
                            const float* __restrict__ x3,
                            const float* __restrict__ w1, const float* __restrict__ b1,
                            const float* __restrict__ w2, const float* __restrict__ b2,
                            const float* __restrict__ w3, const float* __restrict__ b3,
                            float* __restrict__ out_x, float* __restrict__ out_lp) {
    int b = blockIdx.x, t = threadIdx.x;
    __shared__ float g[512], g1[256], g2[128], lg[10];
    __shared__ float lse;
    for (int i = t; i < 512; i += 256)
        g[i] = fmaxf(x1[b * 512 + i], 0.f) + fmaxf(x2[b * 512 + i], 0.f) + fmaxf(x3[b * 512 + i], 0.f);
    __syncthreads();
    {
        float acc = b1[t];
        for (int kk = 0; kk < 512; kk++) acc += g[kk] * w1[kk * 256 + t];
        g1[t] = fmaxf(acc, 0.f);
    }
    __syncthreads();
    if (t < 128) {
        float acc = b2[t];
        for (int kk = 0; kk < 256; kk++) acc += g1[kk] * w2[kk * 128 + t];
        float r = fmaxf(acc, 0.f);
        g2[t] = r;
        out_x[b * 128 + t] = r;
    }
    __syncthreads();
    if (t < 10) {
        float acc = b3[t];
        for (int kk = 0; kk < 128; kk++) acc += g2[kk] * w3[kk * 10 + t];
        lg[t] = acc;
    }
    __syncthreads();
    if (t == 0) {
        float m = -1e30f;
        for (int i = 0; i < 10; i++) m = fmaxf(m, lg[i]);
        float s = 0.f;
        for (int i = 0; i < 10; i++) s += expf(lg[i] - m);
        lse = m + logf(s);
    }
    __syncthreads();
    if (t < 10) out_lp[b * 10 + t] = lg[t] - lse;
}

// ---------------------------------------------------------------------------
extern "C" void kernel_launch(void* const* d_in, const int* in_sizes, int n_in,
                              void* d_out, int out_size, void* d_ws, size_t ws_size,
                              hipStream_t stream) {
    const float* X    = (const float*)d_in[0];
    const int*   EI   = (const int*)d_in[1];
    const float* W1   = (const float*)d_in[3];
    const float* B1v  = (const float*)d_in[4];
    const float* W2   = (const float*)d_in[5];
    const float* B2v  = (const float*)d_in[6];
    const float* W3   = (const float*)d_in[7];
    const float* B3v  = (const float*)d_in[8];
    const float* ATT1 = (const float*)d_in[9];
    const float* ATT2 = (const float*)d_in[10];
    const float* GAM  = (const float*)d_in[11];
    const float* BET  = (const float*)d_in[12];
    const float* MEA  = (const float*)d_in[13];
    const float* VAR  = (const float*)d_in[14];
    const float* L1W  = (const float*)d_in[15];
    const float* L1B  = (const float*)d_in[16];
    const float* L2W  = (const float*)d_in[17];
    const float* L2B  = (const float*)d_in[18];
    const float* L3W  = (const float*)d_in[19];
    const float* L3B  = (const float*)d_in[20];
    float* OUT = (float*)d_out;                 // f32 outputs!
    const int OFF_LOGP = 16384, OFF_XU = 17664;

    const int* src = EI;
    const int* dst = EI + E_;

    uint8_t* w = (uint8_t*)d_ws;
    const size_t MB = 1u << 20;
    float* XWp  = (float*)(w + 0);            // [0,64)
    float* ADJ1 = (float*)(w + 0);            // [0,32)  after XW dead
    float* X2   = (float*)(w + 32 * MB);      // [32,64) after XW dead
    float* X3   = (float*)(w + 32 * MB);      // [32,48) after X2 dead
    float* H3   = (float*)(w + 48 * MB);      // [48,64)
    int*   CSR    = (int*)(w + 68 * MB);      // [68,72)
    int*   INDEG  = (int*)(w + 72 * MB);
    int*   RSTART = INDEG + 65536;
    int*   CURSOR = RSTART + 65536;
    float* DINV   = (float*)(CURSOR + 65536);
    float* SCORE  = (float*)(w + 73 * MB);
    float* H1   = (float*)(w + 76 * MB);      // [76,108) -> reused as H2
    float* H2   = H1;
    float* ADJ2 = (float*)(w + 108 * MB);     // [108,116)
    uint8_t* mp = w + 116 * MB;               // persistent misc
    int*   RANK   = (int*)mp;   mp += 256 * 1024;
    int*   IDX1   = (int*)mp;   mp += 128 * 1024;
    int*   IDX2   = (int*)mp;   mp += 64 * 1024;
    float* E1     = (float*)mp; mp += 128 * 1024;
    float* F1     = (float*)mp; mp += 128 * 1024;
    float* E2     = (float*)mp; mp += 64 * 1024;
    float* F2     = (float*)mp; mp += 64 * 1024;
    float* RS1    = (float*)mp; mp += 128 * 1024;
    float* DV1    = (float*)mp; mp += 128 * 1024;
    float* RS2    = (float*)mp; mp += 64 * 1024;
    float* DV2    = (float*)mp; mp += 64 * 1024;
    float* SC2    = (float*)mp; mp += 128 * 1024;
    float* SBN    = (float*)mp; mp += 4 * 1024;
    float* TBN    = (float*)mp; mp += 4 * 1024;
    float* X1R    = (float*)mp; mp += 256 * 1024;
    float* X2R    = (float*)mp; mp += 256 * 1024;
    float* X3R    = (float*)mp; mp += 256 * 1024;
    ushort_t* WHI = (ushort_t*)mp; mp += 256 * 1024;   // W1^T hi bf16 [256][512]
    ushort_t* WLO = (ushort_t*)mp; mp += 256 * 1024;   // W1^T lo bf16

    float* Hout = OUT + OFF_XU;               // h lives in the x__ output region

    hipMemsetAsync(INDEG, 0, 256 * 1024, stream);
    hipMemsetAsync(RANK, 0xFF, 256 * 1024, stream);
    hipMemsetAsync(SC2, 0, 128 * 1024, stream);
    hipMemsetAsync(X1R, 0, 768 * 1024, stream);  // X1R..X3R zero for atomic readouts

    split_w_kernel<<<512, 256, 0, stream>>>(W1, WHI, WLO);
    gemm_xw_mfma<<<dim3(512, 2), 256, 0, stream>>>(X, WHI, WLO, XWp);
    count_kernel<<<4096, 256, 0, stream>>>(dst, INDEG);
    scan_kernel<<<1, 1024, 0, stream>>>(INDEG, RSTART, CURSOR);
    scatter_csr_kernel<<<4096, 256, 0, stream>>>(src, dst, CURSOR, CSR);
    dinv_kernel<<<256, 256, 0, stream>>>(INDEG, DINV);
    aggregate_kernel<<<16384, 256, 0, stream>>>((const float4*)XWp, RSTART, INDEG, DINV,
                                                CSR, B1v, (float4*)Hout);
    score_kernel<<<16384, 256, 0, stream>>>((const float4*)Hout, RSTART, INDEG, CSR, SCORE);
    topk_kernel<<<128, 512, 0, stream>>>(SCORE, 512, 256, IDX1, RANK, 512);
    gather_rows_kernel<<<32768, 64, 0, stream>>>((const float4*)Hout, IDX1, 256, 512, (float4*)H1);
    readout_kernel<<<dim3(128, 4), 256, 0, stream>>>(H1, 256, X1R);
    ef_plain_kernel<<<8192, 256, 0, stream>>>((const float4*)H1, ATT1, E1, F1);
    hipMemsetAsync(ADJ1, 0, (size_t)32 * MB, stream);
    scatter_A_kernel<<<4096, 256, 0, stream>>>(src, dst, RANK, ADJ1);
    softmax_adj_kernel<<<32768, 256, 0, stream>>>(ADJ1, E1, F1, 256);
    rowsum_kernel<<<8192, 256, 0, stream>>>(ADJ1, 256, RS1, DV1);
    bn_kernel<<<1, 256, 0, stream>>>(GAM, BET, MEA, VAR, SBN, TBN);
    gemm_x2_kernel<<<dim3(4, 4, 128), 256, 0, stream>>>(H1, W2, SBN, TBN, DV1, X2);
    gemm_h2_kernel<<<dim3(4, 4, 128), 256, 0, stream>>>(ADJ1, X2, DV1, B2v, H2);
    gemm_score_kernel<<<dim3(4, 4, 128), 256, 0, stream>>>(ADJ1, H2, RS1, SC2);
    topk_kernel<<<128, 256, 0, stream>>>(SC2, 256, 128, IDX2, nullptr, 0);
    readout_idx_kernel<<<dim3(128, 4), 256, 0, stream>>>(H2, IDX2, 128, 256, X2R);
    ef_idx_kernel<<<4096, 256, 0, stream>>>((const float4*)H2, IDX2, 128, 256, ATT2, E2, F2);
    gather_adj2_kernel<<<dim3(128, 128), 128, 0, stream>>>(ADJ1, IDX2, ADJ2);
    softmax_adj_kernel<<<16384, 128, 0, stream>>>(ADJ2, E2, F2, 128);
    rowsum_kernel<<<4096, 256, 0, stream>>>(ADJ2, 128, RS2, DV2);
    gemm_x3_kernel<<<dim3(2, 4, 128), 256, 0, stream>>>(H2, IDX2, W3, DV2, X3);
    gemm_h3_kernel<<<dim3(2, 4, 128), 256, 0, stream>>>(ADJ2, X3, DV2, B3v, H3);
    readout_kernel<<<dim3(128, 4), 256, 0, stream>>>(H3, 128, X3R);
    head_kernel<<<128, 256, 0, stream>>>(X1R, X2R, X3R, L1W, L1B, L2W, L2B, L3W, L3B,
                                         OUT, OUT + OFF_LOGP);
}

// Round 2
// 1025.699 us; speedup vs baseline: 1.4030x; 1.0224x over previous
//
#include <hip/hip_runtime.h>
#include <stdint.h>

// ---------------------------------------------------------------------------
// HGP-SL GNN forward on MI355X.  Round 8.
//  - ALL batched GEMMs (x2, h2, score2, x3, h3) -> split-bf16 3-term MFMA.
//    Operands materialized in split form ONCE at their producer:
//      * gather+BN writes BN(H1) split (normal [row][k] layout, A-operand)
//      * softmax writes ADJ1 / ADJ2 split directly (fp32 adj dropped)
//      * GEMM epilogues write outputs transposed-split [n][k] (B-operand for
//        the next GEMM).  MFMA kernels: no LDS, no barriers, no conversions --
//        direct 16B fragment loads from L2 + unrolled MFMA.
//  - H2 fp32 dropped; consumers (score values, readout2, ef2, x3-A) use the
//    bf16 hi+lo pair (~2^-17 rel).  Pool-2 readout/ef run on gathered A3 rows.
// Workspace map (MB), peak ~104:
//  [0,64)   XW fp32 (dead after aggregate)
//    then [0,32) IND1 ; then [0,16) X2T(hi,lo 8+8? no: hi[0,16) lo[16,32))
//    then [0,8) A3hi [8,16) A3lo [16,24) ADJ2IND [24,28) ADJ2hi [28,32) ADJ2lo
//  [32,64)  BNH1 split -> H2T split (after x2)
//  [64,96)  H1 fp32 -> ADJ1 split -> X3T split [64,80) + H3 fp32 [80,96)
//  [96,~104.3) CSR + degree arrays + misc persistent
// ---------------------------------------------------------------------------

#define B_   128
#define N_   512
#define NN_  65536
#define E_   1048576
#define LAMB_ 1.0f

typedef unsigned short ushort_t;
typedef __attribute__((ext_vector_type(8))) short bf16x8;
typedef __attribute__((ext_vector_type(8))) unsigned short u16x8;
typedef __attribute__((ext_vector_type(4))) float f32x4;

__device__ inline float waveReduceSum(float v) {
    #pragma unroll
    for (int o = 32; o > 0; o >>= 1) v += __shfl_down(v, o, 64);
    return v;
}
__device__ inline ushort_t f2bf(float f) {
    unsigned u = __float_as_uint(f);
    u += 0x7fffu + ((u >> 16) & 1u);
    return (ushort_t)(u >> 16);
}
__device__ inline void split2(float f, ushort_t& h, ushort_t& l) {
    h = f2bf(f);
    float r = f - __uint_as_float((unsigned)h << 16);
    l = f2bf(r);
}
__device__ inline float bfu(ushort_t s) { return __uint_as_float((unsigned)s << 16); }

// store 4 values (consecutive rows) into transposed split arrays at base
__device__ inline void store_T4(ushort_t* __restrict__ Th, ushort_t* __restrict__ Tl,
                                size_t base, const float* v) {
    ushort_t h[4], l[4];
    #pragma unroll
    for (int r = 0; r < 4; r++) split2(v[r], h[r], l[r]);
    uint2 ph = make_uint2((unsigned)h[0] | ((unsigned)h[1] << 16),
                          (unsigned)h[2] | ((unsigned)h[3] << 16));
    uint2 pl = make_uint2((unsigned)l[0] | ((unsigned)l[1] << 16),
                          (unsigned)l[2] | ((unsigned)l[3] << 16));
    *(uint2*)&Th[base] = ph;
    *(uint2*)&Tl[base] = pl;
}
__device__ inline void load_T4(const ushort_t* __restrict__ Th, const ushort_t* __restrict__ Tl,
                               size_t base, float* v) {
    uint2 ph = *(const uint2*)&Th[base];
    uint2 pl = *(const uint2*)&Tl[base];
    v[0] = __uint_as_float(ph.x << 16) + __uint_as_float(pl.x << 16);
    v[1] = __uint_as_float(ph.x & 0xffff0000u) + __uint_as_float(pl.x & 0xffff0000u);
    v[2] = __uint_as_float(ph.y << 16) + __uint_as_float(pl.y << 16);
    v[3] = __uint_as_float(ph.y & 0xffff0000u) + __uint_as_float(pl.y & 0xffff0000u);
}

// ---------------- pure split-bf16 MFMA core: C(128x128)=A[M][K]@B^T[N][K] ---
// 4 waves of 64x64; fragments loaded direct from global (L2-resident operands).
template<int KSTEPS>
__device__ __attribute__((always_inline)) void mfma_core(
    const ushort_t* __restrict__ Ah, const ushort_t* __restrict__ Al, int lda,
    const ushort_t* __restrict__ Bh, const ushort_t* __restrict__ Bl, int ldb,
    int rowbase, int colbase, int fl, int fh, f32x4 acc[4][4]) {
    #pragma unroll
    for (int ks = 0; ks < KSTEPS; ks++) {
        int kg = ks * 32 + fh * 8;
        bf16x8 bh[4], bl[4];
        #pragma unroll
        for (int ni = 0; ni < 4; ni++) {
            size_t off = (size_t)(colbase + ni * 16 + fl) * ldb + kg;
            bh[ni] = *(const bf16x8*)&Bh[off];
            bl[ni] = *(const bf16x8*)&Bl[off];
        }
        #pragma unroll
        for (int mi = 0; mi < 4; mi++) {
            size_t off = (size_t)(rowbase + mi * 16 + fl) * lda + kg;
            bf16x8 ah = *(const bf16x8*)&Ah[off];
            bf16x8 al = *(const bf16x8*)&Al[off];
            #pragma unroll
            for (int ni = 0; ni < 4; ni++) {
                acc[mi][ni] = __builtin_amdgcn_mfma_f32_16x16x32_bf16(al, bh[ni], acc[mi][ni], 0, 0, 0);
                acc[mi][ni] = __builtin_amdgcn_mfma_f32_16x16x32_bf16(ah, bl[ni], acc[mi][ni], 0, 0, 0);
                acc[mi][ni] = __builtin_amdgcn_mfma_f32_16x16x32_bf16(ah, bh[ni], acc[mi][ni], 0, 0, 0);
            }
        }
    }
}

// ---------------- W split+transpose: W[K][N] -> WT hi/lo [N][K] -------------
__global__ void split_wT_kernel(const float* __restrict__ W, int Kd,
                                ushort_t* __restrict__ Whi, ushort_t* __restrict__ Wlo) {
    int k = blockIdx.x;
    int n = threadIdx.x;
    int Nn = blockDim.x;
    float w = W[k * Nn + n];
    ushort_t h, l;
    split2(w, h, l);
    Whi[n * Kd + k] = h;
    Wlo[n * Kd + k] = l;
}

// ---------------- split-bf16 MFMA GEMM: XW = x @ W1 (65536x512 @ 512x256) ---
// verified round 7: 128x128 tile, 4 waves, BK=32, in-kernel A split via LDS.
__global__ __launch_bounds__(256) void gemm_xw_mfma(
    const float* __restrict__ A, const ushort_t* __restrict__ Bhi,
    const ushort_t* __restrict__ Blo, float* __restrict__ C) {
    int m0 = blockIdx.x * 128, n0 = blockIdx.y * 128;
    __shared__ __align__(16) ushort_t As[2][4][128][8];
    int tid = threadIdx.x;
    int lane = tid & 63, w = tid >> 6;
    int wm = (w & 1) * 64, wn = (w >> 1) * 64;
    int fl = lane & 15, fh = lane >> 4;
    f32x4 acc[4][4] = {};
    int sm = tid >> 1, sk = (tid & 1) * 16;
    const float* Ap = A + (size_t)(m0 + sm) * 512 + sk;
    float4 p0 = *(const float4*)(Ap + 0);
    float4 p1 = *(const float4*)(Ap + 4);
    float4 p2 = *(const float4*)(Ap + 8);
    float4 p3 = *(const float4*)(Ap + 12);
    for (int ks = 0; ks < 16; ks++) {
        float f0[8] = {p0.x, p0.y, p0.z, p0.w, p1.x, p1.y, p1.z, p1.w};
        float f1[8] = {p2.x, p2.y, p2.z, p2.w, p3.x, p3.y, p3.z, p3.w};
        u16x8 h0, h1, l0, l1;
        #pragma unroll
        for (int i = 0; i < 8; i++) {
            ushort_t hh, ll;
            split2(f0[i], hh, ll);
            h0[i] = hh; l0[i] = ll;
        }
        #pragma unroll
        for (int i = 0; i < 8; i++) {
            ushort_t hh, ll;
            split2(f1[i], hh, ll);
            h1[i] = hh; l1[i] = ll;
        }
        __syncthreads();
        int khi = sk >> 3;
        *(u16x8*)&As[0][khi][sm][0]     = h0;
        *(u16x8*)&As[0][khi + 1][sm][0] = h1;
        *(u16x8*)&As[1][khi][sm][0]     = l0;
        *(u16x8*)&As[1][khi + 1][sm][0] = l1;
        __syncthreads();
        if (ks < 15) {
            Ap += 32;
            p0 = *(const float4*)(Ap + 0);
            p1 = *(const float4*)(Ap + 4);
            p2 = *(const float4*)(Ap + 8);
            p3 = *(const float4*)(Ap + 12);
        }
        bf16x8 ah[4], al[4], bh[4], bl[4];
        #pragma unroll
        for (int mi = 0; mi < 4; mi++) {
            ah[mi] = *(const bf16x8*)&As[0][fh][wm + mi * 16 + fl][0];
            al[mi] = *(const bf16x8*)&As[1][fh][wm + mi * 16 + fl][0];
        }
        int kg = ks * 32 + fh * 8;
        #pragma unroll
        for (int ni = 0; ni < 4; ni++) {
            size_t boff = (size_t)(n0 + wn + ni * 16 + fl) * 512 + kg;
            bh[ni] = *(const bf16x8*)&Bhi[boff];
            bl[ni] = *(const bf16x8*)&Blo[boff];
        }
        #pragma unroll
        for (int mi = 0; mi < 4; mi++)
            #pragma unroll
            for (int ni = 0; ni < 4; ni++) {
                acc[mi][ni] = __builtin_amdgcn_mfma_f32_16x16x32_bf16(al[mi], bh[ni], acc[mi][ni], 0, 0, 0);
                acc[mi][ni] = __builtin_amdgcn_mfma_f32_16x16x32_bf16(ah[mi], bl[ni], acc[mi][ni], 0, 0, 0);
                acc[mi][ni] = __builtin_amdgcn_mfma_f32_16x16x32_bf16(ah[mi], bh[ni], acc[mi][ni], 0, 0, 0);
            }
    }
    #pragma unroll
    for (int mi = 0; mi < 4; mi++)
        #pragma unroll
        for (int ni = 0; ni < 4; ni++)
            #pragma unroll
            for (int r = 0; r < 4; r++)
                C[(size_t)(m0 + wm + mi * 16 + fh * 4 + r) * 256 + n0 + wn + ni * 16 + fl]
                    = acc[mi][ni][r];
}

// ---------------- CSR build -------------------------------------------------
__global__ void count_kernel(const int* __restrict__ dst, int* __restrict__ indeg) {
    int e = blockIdx.x * 256 + threadIdx.x;
    if (e < E_) atomicAdd(&indeg[dst[e] & 65535], 1);
}
__global__ void scan_kernel(const int* __restrict__ indeg, int* __restrict__ rowstart,
                            int* __restrict__ cursor) {
    __shared__ int part[1024];
    int t = threadIdx.x;
    int base = t * 64;
    int s = 0;
    for (int i = 0; i < 64; i++) s += indeg[base + i];
    part[t] = s;
    __syncthreads();
    for (int off = 1; off < 1024; off <<= 1) {
        int v = (t >= off) ? part[t - off] : 0;
        __syncthreads();
        part[t] += v;
        __syncthreads();
    }
    int run = (t == 0) ? 0 : part[t - 1];
    for (int i = 0; i < 64; i++) {
        rowstart[base + i] = run;
        cursor[base + i] = run;
        run += indeg[base + i];
    }
}
__global__ void scatter_csr_kernel(const int* __restrict__ src, const int* __restrict__ dst,
                                   int* __restrict__ cursor, int* __restrict__ csr) {
    int e = blockIdx.x * 256 + threadIdx.x;
    if (e < E_) {
        int pos = atomicAdd(&cursor[dst[e] & 65535], 1);
        csr[pos & (E_ - 1)] = src[e] & 65535;
    }
}
__global__ void dinv_kernel(const int* __restrict__ indeg, float* __restrict__ dinv) {
    int i = blockIdx.x * 256 + threadIdx.x;
    dinv[i] = rsqrtf((float)indeg[i] + 1.0f);
}

// ---------------- sparse GCN aggregate --------------------------------------
__global__ void aggregate_kernel(const float4* __restrict__ xw, const int* __restrict__ rowstart,
                                 const int* __restrict__ indeg, const float* __restrict__ dinv,
                                 const int* __restrict__ csr, const float* __restrict__ b1,
                                 float4* __restrict__ hout) {
    int bid = (blockIdx.x & 7) * 2048 + (blockIdx.x >> 3);
    int node = bid * 4 + (threadIdx.x >> 6);
    int lane = threadIdx.x & 63;
    int beg = rowstart[node], cnt = indeg[node];
    float di = dinv[node];
    float4 acc = make_float4(0.f, 0.f, 0.f, 0.f);
    for (int t = 0; t < cnt; t++) {
        int s = csr[(beg + t) & (E_ - 1)] & 65535;
        float w = dinv[s] * di;
        float4 v = xw[(size_t)s * 64 + lane];
        acc.x += v.x * w; acc.y += v.y * w; acc.z += v.z * w; acc.w += v.w * w;
    }
    {
        float w = di * di;
        float4 v = xw[(size_t)node * 64 + lane];
        acc.x += v.x * w; acc.y += v.y * w; acc.z += v.z * w; acc.w += v.w * w;
    }
    int c4 = lane * 4;
    acc.x = fmaxf(acc.x + b1[c4 + 0], 0.f);
    acc.y = fmaxf(acc.y + b1[c4 + 1], 0.f);
    acc.z = fmaxf(acc.z + b1[c4 + 2], 0.f);
    acc.w = fmaxf(acc.w + b1[c4 + 3], 0.f);
    hout[(size_t)node * 64 + lane] = acc;
}

// ---------------- pool_sparse score -----------------------------------------
__global__ void score_kernel(const float4* __restrict__ h, const int* __restrict__ rowstart,
                             const int* __restrict__ indeg, const int* __restrict__ csr,
                             float* __restrict__ score) {
    int bid = (blockIdx.x & 7) * 2048 + (blockIdx.x >> 3);
    int node = bid * 4 + (threadIdx.x >> 6);
    int lane = threadIdx.x & 63;
    int beg = rowstart[node], cnt = indeg[node];
    float degp = fmaxf((float)cnt, 1.0f);
    float4 nb = make_float4(0.f, 0.f, 0.f, 0.f);
    for (int t = 0; t < cnt; t++) {
        int s = csr[(beg + t) & (E_ - 1)] & 65535;
        float4 v = h[(size_t)s * 64 + lane];
        nb.x += v.x; nb.y += v.y; nb.z += v.z; nb.w += v.w;
    }
    float4 x = h[(size_t)node * 64 + lane];
    float p = fabsf(x.x - nb.x / degp) + fabsf(x.y - nb.y / degp) +
              fabsf(x.z - nb.z / degp) + fabsf(x.w - nb.w / degp);
    p = waveReduceSum(p);
    if (lane == 0) score[node] = p;
}

// ---------------- bitonic top-k ---------------------------------------------
__global__ void topk_kernel(const float* __restrict__ score, int n, int k,
                            int* __restrict__ out_local, int* __restrict__ rank, int Nfull) {
    int b = blockIdx.x, i = threadIdx.x;
    __shared__ float ss[512];
    __shared__ int si[512];
    ss[i] = score[b * n + i];
    si[i] = i;
    __syncthreads();
    for (int kk = 2; kk <= n; kk <<= 1)
        for (int j = kk >> 1; j > 0; j >>= 1) {
            int l = i ^ j;
            if (l > i) {
                float s1 = ss[i], s2 = ss[l];
                int i1 = si[i], i2 = si[l];
                bool up = ((i & kk) == 0);
                bool before = (s1 > s2) || (s1 == s2 && i1 < i2);
                bool doswap = up ? (!before) : before;
                if (doswap) { ss[i] = s2; ss[l] = s1; si[i] = i2; si[l] = i1; }
            }
            __syncthreads();
        }
    if (i < k) {
        int loc = si[i];
        out_local[b * k + i] = loc;
        if (rank) rank[b * Nfull + loc] = i;
    }
}

// ---------------- gather + BN + split (pool-1) ------------------------------
__global__ void gather_bn_kernel(const float4* __restrict__ src, const int* __restrict__ idxl,
                                 const float* __restrict__ sBN, const float* __restrict__ tBN,
                                 float4* __restrict__ H1, ushort_t* __restrict__ BNh,
                                 ushort_t* __restrict__ BNl) {
    int row = blockIdx.x;      // B*256
    int b = row >> 8;
    int node = b * 512 + (idxl[row] & 511);
    int lane = threadIdx.x;    // 64
    float4 v = src[(size_t)node * 64 + lane];
    H1[(size_t)row * 64 + lane] = v;
    int c0 = lane * 4;
    float bn[4];
    bn[0] = v.x * sBN[c0 + 0] + tBN[c0 + 0];
    bn[1] = v.y * sBN[c0 + 1] + tBN[c0 + 1];
    bn[2] = v.z * sBN[c0 + 2] + tBN[c0 + 2];
    bn[3] = v.w * sBN[c0 + 3] + tBN[c0 + 3];
    ushort_t h[4], l[4];
    #pragma unroll
    for (int j = 0; j < 4; j++) split2(bn[j], h[j], l[j]);
    uint2 ph = make_uint2((unsigned)h[0] | ((unsigned)h[1] << 16),
                          (unsigned)h[2] | ((unsigned)h[3] << 16));
    uint2 pl = make_uint2((unsigned)l[0] | ((unsigned)l[1] << 16),
                          (unsigned)l[2] | ((unsigned)l[3] << 16));
    *(uint2*)&BNh[(size_t)row * 256 + c0] = ph;
    *(uint2*)&BNl[(size_t)row * 256 + c0] = pl;
}

// ---------------- readouts / e-f dots ---------------------------------------
__global__ void readout_kernel(const float* __restrict__ x, int k, float* __restrict__ out) {
    int b = blockIdx.x, q = blockIdx.y, c = threadIdx.x;
    int chunk = k >> 2;
    int j0 = q * chunk;
    float mx = 0.f, sm = 0.f;
    for (int j = j0; j < j0 + chunk; j++) {
        float v = x[((size_t)(b * k + j)) * 256 + c];
        mx = fmaxf(mx, v);
        sm += v;
    }
    atomicMax((unsigned int*)&out[b * 512 + c], __float_as_uint(mx));
    atomicAdd(&out[b * 512 + 256 + c], sm * (1.0f / (float)k));
}
__global__ void readout_split_kernel(const ushort_t* __restrict__ Ah,
                                     const ushort_t* __restrict__ Al,
                                     int k, float* __restrict__ out) {
    int b = blockIdx.x, q = blockIdx.y, c = threadIdx.x;
    int chunk = k >> 2;
    int j0 = q * chunk;
    float mx = 0.f, sm = 0.f;
    for (int j = j0; j < j0 + chunk; j++) {
        size_t idx = ((size_t)(b * k + j)) * 256 + c;
        float v = bfu(Ah[idx]) + bfu(Al[idx]);
        mx = fmaxf(mx, v);
        sm += v;
    }
    atomicMax((unsigned int*)&out[b * 512 + c], __float_as_uint(mx));
    atomicAdd(&out[b * 512 + 256 + c], sm * (1.0f / (float)k));
}
__global__ void ef_plain_kernel(const float4* __restrict__ x, const float* __restrict__ att,
                                float* __restrict__ e, float* __restrict__ f) {
    int row = blockIdx.x * 4 + (threadIdx.x >> 6);
    int lane = threadIdx.x & 63;
    float4 v = x[(size_t)row * 64 + lane];
    const float* ap = att + lane * 8;
    float es = v.x * ap[0] + v.y * ap[2] + v.z * ap[4] + v.w * ap[6];
    float fs = v.x * ap[1] + v.y * ap[3] + v.z * ap[5] + v.w * ap[7];
    es = waveReduceSum(es);
    fs = waveReduceSum(fs);
    if (lane == 0) { e[row] = es; f[row] = fs; }
}
__global__ void ef_split_kernel(const ushort_t* __restrict__ Ah, const ushort_t* __restrict__ Al,
                                const float* __restrict__ att,
                                float* __restrict__ e, float* __restrict__ f) {
    int row = blockIdx.x * 4 + (threadIdx.x >> 6);
    int lane = threadIdx.x & 63;
    size_t base = (size_t)row * 256 + lane * 4;
    float v[4];
    load_T4(Ah, Al, base, v);
    const float* ap = att + lane * 8;
    float es = v[0] * ap[0] + v[1] * ap[2] + v[2] * ap[4] + v[3] * ap[6];
    float fs = v[0] * ap[1] + v[1] * ap[3] + v[2] * ap[5] + v[3] * ap[7];
    es = waveReduceSum(es);
    fs = waveReduceSum(fs);
    if (lane == 0) { e[row] = es; f[row] = fs; }
}

// ---------------- A_ind scatter / softmax-split / rowsums -------------------
__global__ void scatter_A_kernel(const int* __restrict__ src, const int* __restrict__ dst,
                                 const int* __restrict__ rank, float* __restrict__ adj1) {
    int e = blockIdx.x * 256 + threadIdx.x;
    if (e >= E_) return;
    int s = src[e] & 65535, d = dst[e] & 65535;
    int ns = rank[s], nd = rank[d];
    if ((unsigned)ns < 256u && (unsigned)nd < 256u) {
        int g = s >> 9;
        adj1[(size_t)g * 65536 + ns * 256 + nd] = 1.0f;
    }
}
__global__ void softmax_split_kernel(const float* __restrict__ ind, const float* __restrict__ e,
                                     const float* __restrict__ f, int k,
                                     ushort_t* __restrict__ oh, ushort_t* __restrict__ ol) {
    int row = blockIdx.x;
    int b = row / k;
    int c = threadIdx.x;
    __shared__ float red[256];
    float v = ind[(size_t)row * k + c];
    float lg = e[row] + f[b * k + c] + LAMB_ * v;
    red[c] = lg;
    __syncthreads();
    for (int s = k >> 1; s > 0; s >>= 1) {
        if (c < s) red[c] = fmaxf(red[c], red[c + s]);
        __syncthreads();
    }
    float mx = red[0];
    __syncthreads();
    float ex = expf(lg - mx);
    red[c] = ex;
    __syncthreads();
    for (int s = k >> 1; s > 0; s >>= 1) {
        if (c < s) red[c] += red[c + s];
        __syncthreads();
    }
    float p = ex / red[0];
    ushort_t h, l;
    split2(p, h, l);
    oh[(size_t)row * k + c] = h;
    ol[(size_t)row * k + c] = l;
}
__global__ void rowsum_split_kernel(const ushort_t* __restrict__ Ah,
                                    const ushort_t* __restrict__ Al, int k,
                                    float* __restrict__ rowsum, float* __restrict__ dinv) {
    int row = blockIdx.x * 4 + (threadIdx.x >> 6);
    int lane = threadIdx.x & 63;
    float s = 0.f;
    for (int c = lane; c < k; c += 64) {
        size_t idx = (size_t)row * k + c;
        s += bfu(Ah[idx]) + bfu(Al[idx]);
    }
    s = waveReduceSum(s);
    if (lane == 0) { rowsum[row] = s; dinv[row] = rsqrtf(s + 1.0f); }
}
__global__ void gather_adj2_split_kernel(const ushort_t* __restrict__ Ah,
                                         const ushort_t* __restrict__ Al,
                                         const int* __restrict__ idx2,
                                         float* __restrict__ adj2) {
    int ii = blockIdx.x, b = blockIdx.y, jj = threadIdx.x;
    int ri = idx2[b * 128 + ii] & 255, rj = idx2[b * 128 + jj] & 255;
    size_t idx = (size_t)b * 65536 + ri * 256 + rj;
    adj2[((size_t)(b * 128 + ii)) * 128 + jj] = bfu(Ah[idx]) + bfu(Al[idx]);
}
__global__ void bn_kernel(const float* g, const float* be,
                          const float* me, const float* va,
                          float* sBN, float* tBN) {
    int c = threadIdx.x;
    float s = g[c] * rsqrtf(va[c] + 1e-5f);
    sBN[c] = s;
    tBN[c] = be[c] - me[c] * s;
}

// ---------------- A3 = H2 rows (idx2) in split normal layout ----------------
__global__ void gather_a3_kernel(const ushort_t* __restrict__ H2Th,
                                 const ushort_t* __restrict__ H2Tl,
                                 const int* __restrict__ idx2,
                                 ushort_t* __restrict__ A3h, ushort_t* __restrict__ A3l) {
    int row = blockIdx.x;     // B*128
    int b = row >> 7;
    int node = idx2[row] & 255;
    int lane = threadIdx.x;   // 64
    int c0 = lane * 4;
    unsigned h[4], l[4];
    #pragma unroll
    for (int j = 0; j < 4; j++) {
        size_t idx = ((size_t)(b * 256 + c0 + j)) * 256 + node;
        h[j] = H2Th[idx];
        l[j] = H2Tl[idx];
    }
    uint2 ph = make_uint2(h[0] | (h[1] << 16), h[2] | (h[3] << 16));
    uint2 pl = make_uint2(l[0] | (l[1] << 16), l[2] | (l[3] << 16));
    *(uint2*)&A3h[(size_t)row * 256 + c0] = ph;
    *(uint2*)&A3l[(size_t)row * 256 + c0] = pl;
}

// ---------------- batched MFMA GEMMs ----------------------------------------
// (a) X2T = (dinv1_row * (BN(H1) @ W2))^T, stored split [n][m]
__global__ __launch_bounds__(256) void gemm_x2_mfma(
    const ushort_t* __restrict__ Ah, const ushort_t* __restrict__ Al,
    const ushort_t* __restrict__ Bh, const ushort_t* __restrict__ Bl,
    const float* __restrict__ dinv1,
    ushort_t* __restrict__ XTh, ushort_t* __restrict__ XTl) {
    int b = blockIdx.z;
    int m0 = blockIdx.x * 128, n0 = blockIdx.y * 128;
    int lane = threadIdx.x & 63, w = threadIdx.x >> 6;
    int wm = (w & 1) * 64, wn = (w >> 1) * 64;
    int fl = lane & 15, fh = lane >> 4;
    f32x4 acc[4][4] = {};
    mfma_core<8>(Ah + (size_t)b * 65536, Al + (size_t)b * 65536, 256,
                 Bh, Bl, 256, m0 + wm, n0 + wn, fl, fh, acc);
    #pragma unroll
    for (int mi = 0; mi < 4; mi++) {
        int row0 = m0 + wm + mi * 16 + fh * 4;
        float4 dv = *(const float4*)&dinv1[b * 256 + row0];
        float dvv[4] = {dv.x, dv.y, dv.z, dv.w};
        #pragma unroll
        for (int ni = 0; ni < 4; ni++) {
            int col = n0 + wn + ni * 16 + fl;
            float v[4];
            #pragma unroll
            for (int r = 0; r < 4; r++) v[r] = acc[mi][ni][r] * dvv[r];
            store_T4(XTh, XTl, ((size_t)(b * 256 + col)) * 256 + row0, v);
        }
    }
}

// (b) H2T = relu(dinv1_i*(ADJ1@X2 + X2_i) + b2)^T, stored split [n][m]
__global__ __launch_bounds__(256) void gemm_h2_mfma(
    const ushort_t* __restrict__ Ah, const ushort_t* __restrict__ Al,
    const ushort_t* __restrict__ Xh, const ushort_t* __restrict__ Xl,
    const float* __restrict__ dinv1, const float* __restrict__ b2,
    ushort_t* __restrict__ Hh, ushort_t* __restrict__ Hl) {
    int b = blockIdx.z;
    int m0 = blockIdx.x * 128, n0 = blockIdx.y * 128;
    int lane = threadIdx.x & 63, w = threadIdx.x >> 6;
    int wm = (w & 1) * 64, wn = (w >> 1) * 64;
    int fl = lane & 15, fh = lane >> 4;
    f32x4 acc[4][4] = {};
    mfma_core<8>(Ah + (size_t)b * 65536, Al + (size_t)b * 65536, 256,
                 Xh + (size_t)b * 65536, Xl + (size_t)b * 65536, 256,
                 m0 + wm, n0 + wn, fl, fh, acc);
    #pragma unroll
    for (int mi = 0; mi < 4; mi++) {
        int row0 = m0 + wm + mi * 16 + fh * 4;
        float4 dv = *(const float4*)&dinv1[b * 256 + row0];
        float dvv[4] = {dv.x, dv.y, dv.z, dv.w};
        #pragma unroll
        for (int ni = 0; ni < 4; ni++) {
            int col = n0 + wn + ni * 16 + fl;
            size_t baseT = ((size_t)(b * 256 + col)) * 256 + row0;
            float xv[4], v[4];
            load_T4(Xh, Xl, baseT, xv);
            float bc = b2[col];
            #pragma unroll
            for (int r = 0; r < 4; r++)
                v[r] = fmaxf((acc[mi][ni][r] + xv[r]) * dvv[r] + bc, 0.f);
            store_T4(Hh, Hl, baseT, v);
        }
    }
}

// (c) score2 += sum_cols |H2 - (ADJ1@H2)/deg|
__global__ __launch_bounds__(256) void gemm_score_mfma(
    const ushort_t* __restrict__ Ah, const ushort_t* __restrict__ Al,
    const ushort_t* __restrict__ Hh, const ushort_t* __restrict__ Hl,
    const float* __restrict__ rowsum1, float* __restrict__ score2) {
    int b = blockIdx.z;
    int m0 = blockIdx.x * 128, n0 = blockIdx.y * 128;
    int lane = threadIdx.x & 63, w = threadIdx.x >> 6;
    int wm = (w & 1) * 64, wn = (w >> 1) * 64;
    int fl = lane & 15, fh = lane >> 4;
    f32x4 acc[4][4] = {};
    mfma_core<8>(Ah + (size_t)b * 65536, Al + (size_t)b * 65536, 256,
                 Hh + (size_t)b * 65536, Hl + (size_t)b * 65536, 256,
                 m0 + wm, n0 + wn, fl, fh, acc);
    float part[4][4];
    #pragma unroll
    for (int mi = 0; mi < 4; mi++)
        #pragma unroll
        for (int r = 0; r < 4; r++) part[mi][r] = 0.f;
    #pragma unroll
    for (int mi = 0; mi < 4; mi++) {
        int row0 = m0 + wm + mi * 16 + fh * 4;
        float4 rs = *(const float4*)&rowsum1[b * 256 + row0];
        float rd[4] = {1.0f / fmaxf(rs.x, 1e-9f), 1.0f / fmaxf(rs.y, 1e-9f),
                       1.0f / fmaxf(rs.z, 1e-9f), 1.0f / fmaxf(rs.w, 1e-9f)};
        #pragma unroll
        for (int ni = 0; ni < 4; ni++) {
            int col = n0 + wn + ni * 16 + fl;
            size_t baseT = ((size_t)(b * 256 + col)) * 256 + row0;
            float hv[4];
            load_T4(Hh, Hl, baseT, hv);
            #pragma unroll
            for (int r = 0; r < 4; r++)
                part[mi][r] += fabsf(hv[r] - acc[mi][ni][r] * rd[r]);
        }
    }
    #pragma unroll
    for (int mi = 0; mi < 4; mi++) {
        int row0 = m0 + wm + mi * 16 + fh * 4;
        #pragma unroll
        for (int r = 0; r < 4; r++) {
            float s = part[mi][r];
            #pragma unroll
            for (int o = 8; o >= 1; o >>= 1) s += __shfl_xor(s, o, 64);
            if (fl == 0) atomicAdd(&score2[b * 256 + row0 + r], s);
        }
    }
}

// (d) X3T = (dinv2_row * (A3 @ W3))^T, stored split [n=256][m=128]
__global__ __launch_bounds__(256) void gemm_x3_mfma(
    const ushort_t* __restrict__ Ah, const ushort_t* __restrict__ Al,
    const ushort_t* __restrict__ Bh, const ushort_t* __restrict__ Bl,
    const float* __restrict__ dinv2,
    ushort_t* __restrict__ XTh, ushort_t* __restrict__ XTl) {
    int b = blockIdx.z;
    int m0 = blockIdx.x * 128, n0 = blockIdx.y * 128;
    int lane = threadIdx.x & 63, w = threadIdx.x >> 6;
    int wm = (w & 1) * 64, wn = (w >> 1) * 64;
    int fl = lane & 15, fh = lane >> 4;
    f32x4 acc[4][4] = {};
    mfma_core<8>(Ah + (size_t)b * 32768, Al + (size_t)b * 32768, 256,
                 Bh, Bl, 256, m0 + wm, n0 + wn, fl, fh, acc);
    #pragma unroll
    for (int mi = 0; mi < 4; mi++) {
        int row0 = m0 + wm + mi * 16 + fh * 4;
        float4 dv = *(const float4*)&dinv2[b * 128 + row0];
        float dvv[4] = {dv.x, dv.y, dv.z, dv.w};
        #pragma unroll
        for (int ni = 0; ni < 4; ni++) {
            int col = n0 + wn + ni * 16 + fl;
            float v[4];
            #pragma unroll
            for (int r = 0; r < 4; r++) v[r] = acc[mi][ni][r] * dvv[r];
            store_T4(XTh, XTl, ((size_t)(b * 256 + col)) * 128 + row0, v);
        }
    }
}

// (e) H3 = relu(dinv2_i*(ADJ2@X3 + X3_i) + b3), fp32 normal layout
__global__ __launch_bounds__(256) void gemm_h3_mfma(
    const ushort_t* __restrict__ Ah, const ushort_t* __restrict__ Al,
    const ushort_t* __restrict__ Xh, const ushort_t* __restrict__ Xl,
    const float* __restrict__ dinv2, const float* __restrict__ b3,
    float* __restrict__ H3) {
    int b = blockIdx.z;
    int m0 = blockIdx.x * 128, n0 = blockIdx.y * 128;
    int lane = threadIdx.x & 63, w = threadIdx.x >> 6;
    int wm = (w & 1) * 64, wn = (w >> 1) * 64;
    int fl = lane & 15, fh = lane >> 4;
    f32x4 acc[4][4] = {};
    mfma_core<4>(Ah + (size_t)b * 16384, Al + (size_t)b * 16384, 128,
                 Xh + (size_t)b * 32768, Xl + (size_t)b * 32768, 128,
                 m0 + wm, n0 + wn, fl, fh, acc);
    #pragma unroll
    for (int mi = 0; mi < 4; mi++) {
        int row0 = m0 + wm + mi * 16 + fh * 4;
        float4 dv = *(const float4*)&dinv2[b * 128 + row0];
        float dvv[4] = {dv.x, dv.y, dv.z, dv.w};
        #pragma unroll
        for (int ni = 0; ni < 4; ni++) {
            int col = n0 + wn + ni * 16 + fl;
            size_t baseT = ((size_t)(b * 256 + col)) * 128 + row0;
            float xv[4];
            load_T4(Xh, Xl, baseT, xv);
            float bc = b3[col];
            #pragma unroll
            for (int r = 0; r < 4; r++) {
                float v = fmaxf((acc[mi][ni][r] + xv[r]) * dvv[r] + bc, 0.f);
                H3[(size_t)b * 32768 + (size_t)(row0 + r) * 256 + col] = v;
            }
        }
    }
}

// ---------------- head MLP (f32 outputs) ------------------------------------
__global__ void head_kernel(const float* __restrict__ x1, const float* __restrict__ x2,
                            const float* __restrict__ x3,
                            const float* __restrict__ w1, const float* __restrict__ b1,
                            const float* __restrict__ w2, const float* __restrict__ b2,
                            const float* __restrict__ w3, const float* __restrict__ b3,
                            float* __restrict__ out_x, float* __restrict__ out_lp) {
    int b = blockIdx.x, t = threadIdx.x;
    __shared__ float g[512], g1[256], g2[128], lg[10];
    __shared__ float lse;
    for (int i = t; i < 512; i += 256)
        g[i] = fmaxf(x1[b * 512 + i], 0.f) + fmaxf(x2[b * 512 + i], 0.f) + fmaxf(x3[b * 512 + i], 0.f);
    __syncthreads();
    {
        float acc = b1[t];
        for (int kk = 0; kk < 512; kk++) acc += g[kk] * w1[kk * 256 + t];
        g1[t] = fmaxf(acc, 0.f);
    }
    __syncthreads();
    if (t < 128) {
        float acc = b2[t];
        for (int kk = 0; kk < 256; kk++) acc += g1[kk] * w2[kk * 128 + t];
        float r = fmaxf(acc, 0.f);
        g2[t] = r;
        out_x[b * 128 + t] = r;
    }
    __syncthreads();
    if (t < 10) {
        float acc = b3[t];
        for (int kk = 0; kk < 128; kk++) acc += g2[kk] * w3[kk * 10 + t];
        lg[t] = acc;
    }
    __syncthreads();
    if (t == 0) {
        float m = -1e30f;
        for (int i = 0; i < 10; i++) m = fmaxf(m, lg[i]);
        float s = 0.f;
        for (int i = 0; i < 10; i++) s += expf(lg[i] - m);
        lse = m + logf(s);
    }
    __syncthreads();
    if (t < 10) out_lp[b * 10 + t] = lg[t] - lse;
}

// ---------------------------------------------------------------------------
extern "C" void kernel_launch(void* const* d_in, const int* in_sizes, int n_in,
                              void* d_out, int out_size, void* d_ws, size_t ws_size,
                              hipStream_t stream) {
    const float* X    = (const float*)d_in[0];
    const int*   EI   = (const int*)d_in[1];
    const float* W1   = (const float*)d_in[3];
    const float* B1v  = (const float*)d_in[4];
    const float* W2   = (const float*)d_in[5];
    const float* B2v  = (const float*)d_in[6];
    const float* W3   = (const float*)d_in[7];
    const float* B3v  = (const float*)d_in[8];
    const float* ATT1 = (const float*)d_in[9];
    const float* ATT2 = (const float*)d_in[10];
    const float* GAM  = (const float*)d_in[11];
    const float* BET  = (const float*)d_in[12];
    const float* MEA  = (const float*)d_in[13];
    const float* VAR  = (const float*)d_in[14];
    const float* L1W  = (const float*)d_in[15];
    const float* L1B  = (const float*)d_in[16];
    const float* L2W  = (const float*)d_in[17];
    const float* L2B  = (const float*)d_in[18];
    const float* L3W  = (const float*)d_in[19];
    const float* L3B  = (const float*)d_in[20];
    float* OUT = (float*)d_out;                 // f32 outputs
    const int OFF_LOGP = 16384, OFF_XU = 17664;

    const int* src = EI;
    const int* dst = EI + E_;

    uint8_t* w = (uint8_t*)d_ws;
    const size_t MB = 1u << 20;
    // region [0,64): XW -> IND1 -> X2T -> {A3, ADJ2IND, ADJ2 split}
    float*    XWp     = (float*)(w + 0);
    float*    IND1    = (float*)(w + 0);
    ushort_t* X2TH    = (ushort_t*)(w + 0);
    ushort_t* X2TL    = (ushort_t*)(w + 16 * MB);
    ushort_t* A3H     = (ushort_t*)(w + 0);
    ushort_t* A3L     = (ushort_t*)(w + 8 * MB);
    float*    ADJ2IND = (float*)(w + 16 * MB);
    ushort_t* ADJ2H   = (ushort_t*)(w + 24 * MB);
    ushort_t* ADJ2L   = (ushort_t*)(w + 28 * MB);
    // region [32,64): BNH1 split -> H2T split
    ushort_t* BNH1H   = (ushort_t*)(w + 32 * MB);
    ushort_t* BNH1L   = (ushort_t*)(w + 48 * MB);
    ushort_t* H2TH    = (ushort_t*)(w + 32 * MB);
    ushort_t* H2TL    = (ushort_t*)(w + 48 * MB);
    // region [64,96): H1 fp32 -> ADJ1 split -> {X3T split, H3 fp32}
    float*    H1      = (float*)(w + 64 * MB);
    ushort_t* ADJ1H   = (ushort_t*)(w + 64 * MB);
    ushort_t* ADJ1L   = (ushort_t*)(w + 80 * MB);
    ushort_t* X3TH    = (ushort_t*)(w + 64 * MB);
    ushort_t* X3TL    = (ushort_t*)(w + 72 * MB);
    float*    H3      = (float*)(w + 80 * MB);
    // region [96,...): persistent misc
    int*   CSR    = (int*)(w + 96 * MB);                  // 4 MB
    int*   INDEG  = (int*)(w + 100 * MB);
    int*   RSTART = INDEG + 65536;
    int*   CURSOR = RSTART + 65536;
    float* DINV   = (float*)(CURSOR + 65536);
    float* SCORE  = (float*)(w + 101 * MB);               // 256 KB
    uint8_t* mp = w + 101 * MB + 256 * 1024;
    int*   RANK   = (int*)mp;   mp += 256 * 1024;
    int*   IDX1   = (int*)mp;   mp += 128 * 1024;
    int*   IDX2   = (int*)mp;   mp += 64 * 1024;
    float* E1     = (float*)mp; mp += 128 * 1024;
    float* F1     = (float*)mp; mp += 128 * 1024;
    float* E2     = (float*)mp; mp += 64 * 1024;
    float* F2     = (float*)mp; mp += 64 * 1024;
    float* RS1    = (float*)mp; mp += 128 * 1024;
    float* DV1    = (float*)mp; mp += 128 * 1024;
    float* RS2    = (float*)mp; mp += 64 * 1024;
    float* DV2    = (float*)mp; mp += 64 * 1024;
    float* SC2    = (float*)mp; mp += 128 * 1024;
    float* SBN    = (float*)mp; mp += 4 * 1024;
    float* TBN    = (float*)mp; mp += 4 * 1024;
    float* X1R    = (float*)mp; mp += 256 * 1024;
    float* X2R    = (float*)mp; mp += 256 * 1024;
    float* X3R    = (float*)mp; mp += 256 * 1024;
    ushort_t* W1TH = (ushort_t*)mp; mp += 256 * 1024;     // [256][512]
    ushort_t* W1TL = (ushort_t*)mp; mp += 256 * 1024;
    ushort_t* W2TH = (ushort_t*)mp; mp += 128 * 1024;     // [256][256]
    ushort_t* W2TL = (ushort_t*)mp; mp += 128 * 1024;
    ushort_t* W3TH = (ushort_t*)mp; mp += 128 * 1024;
    ushort_t* W3TL = (ushort_t*)mp; mp += 128 * 1024;

    float* Hout = OUT + OFF_XU;               // h lives in the x__ output region

    hipMemsetAsync(INDEG, 0, 256 * 1024, stream);
    hipMemsetAsync(RANK, 0xFF, 256 * 1024, stream);
    hipMemsetAsync(SC2, 0, 128 * 1024, stream);
    hipMemsetAsync(X1R, 0, 768 * 1024, stream);   // X1R..X3R zero for atomic readouts

    bn_kernel<<<1, 256, 0, stream>>>(GAM, BET, MEA, VAR, SBN, TBN);
    split_wT_kernel<<<512, 256, 0, stream>>>(W1, 512, W1TH, W1TL);
    split_wT_kernel<<<256, 256, 0, stream>>>(W2, 256, W2TH, W2TL);
    split_wT_kernel<<<256, 256, 0, stream>>>(W3, 256, W3TH, W3TL);

    gemm_xw_mfma<<<dim3(512, 2), 256, 0, stream>>>(X, W1TH, W1TL, XWp);
    count_kernel<<<4096, 256, 0, stream>>>(dst, INDEG);
    scan_kernel<<<1, 1024, 0, stream>>>(INDEG, RSTART, CURSOR);
    scatter_csr_kernel<<<4096, 256, 0, stream>>>(src, dst, CURSOR, CSR);
    dinv_kernel<<<256, 256, 0, stream>>>(INDEG, DINV);
    aggregate_kernel<<<16384, 256, 0, stream>>>((const float4*)XWp, RSTART, INDEG, DINV,
                                                CSR, B1v, (float4*)Hout);
    score_kernel<<<16384, 256, 0, stream>>>((const float4*)Hout, RSTART, INDEG, CSR, SCORE);
    topk_kernel<<<128, 512, 0, stream>>>(SCORE, 512, 256, IDX1, RANK, 512);
    gather_bn_kernel<<<32768, 64, 0, stream>>>((const float4*)Hout, IDX1, SBN, TBN,
                                               (float4*)H1, BNH1H, BNH1L);
    readout_kernel<<<dim3(128, 4), 256, 0, stream>>>(H1, 256, X1R);
    ef_plain_kernel<<<8192, 256, 0, stream>>>((const float4*)H1, ATT1, E1, F1);
    hipMemsetAsync(IND1, 0, (size_t)32 * MB, stream);     // XW dead (post-aggregate)
    scatter_A_kernel<<<4096, 256, 0, stream>>>(src, dst, RANK, IND1);
    softmax_split_kernel<<<32768, 256, 0, stream>>>(IND1, E1, F1, 256, ADJ1H, ADJ1L);
    rowsum_split_kernel<<<8192, 256, 0, stream>>>(ADJ1H, ADJ1L, 256, RS1, DV1);
    gemm_x2_mfma<<<dim3(2, 2, 128), 256, 0, stream>>>(BNH1H, BNH1L, W2TH, W2TL, DV1,
                                                      X2TH, X2TL);
    gemm_h2_mfma<<<dim3(2, 2, 128), 256, 0, stream>>>(ADJ1H, ADJ1L, X2TH, X2TL, DV1, B2v,
                                                      H2TH, H2TL);
    gemm_score_mfma<<<dim3(2, 2, 128), 256, 0, stream>>>(ADJ1H, ADJ1L, H2TH, H2TL, RS1, SC2);
    topk_kernel<<<128, 256, 0, stream>>>(SC2, 256, 128, IDX2, nullptr, 0);
    gather_a3_kernel<<<16384, 64, 0, stream>>>(H2TH, H2TL, IDX2, A3H, A3L);
    readout_split_kernel<<<dim3(128, 4), 256, 0, stream>>>(A3H, A3L, 128, X2R);
    ef_split_kernel<<<4096, 256, 0, stream>>>(A3H, A3L, ATT2, E2, F2);
    gather_adj2_split_kernel<<<dim3(128, 128), 128, 0, stream>>>(ADJ1H, ADJ1L, IDX2, ADJ2IND);
    softmax_split_kernel<<<16384, 128, 0, stream>>>(ADJ2IND, E2, F2, 128, ADJ2H, ADJ2L);
    rowsum_split_kernel<<<4096, 256, 0, stream>>>(ADJ2H, ADJ2L, 128, RS2, DV2);
    gemm_x3_mfma<<<dim3(1, 2, 128), 256, 0, stream>>>(A3H, A3L, W3TH, W3TL, DV2, X3TH, X3TL);
    gemm_h3_mfma<<<dim3(1, 2, 128), 256, 0, stream>>>(ADJ2H, ADJ2L, X3TH, X3TL, DV2, B3v, H3);
    readout_kernel<<<dim3(128, 4), 256, 0, stream>>>(H3, 128, X3R);
    head_kernel<<<128, 256, 0, stream>>>(X1R, X2R, X3R, L1W, L1B, L2W, L2B, L3W, L3B,
                                         OUT, OUT + OFF_LOGP);
}

// Round 3
// 1013.106 us; speedup vs baseline: 1.4204x; 1.0124x over previous
//
#include <hip/hip_runtime.h>
#include <stdint.h>

// ---------------------------------------------------------------------------
// HGP-SL GNN forward on MI355X.  Round 9.
//  - gemm_xw: barrier-free, LDS-free. Each lane loads its own A fragment
//    (8 consecutive fp32 of one row) direct from global and splits to bf16
//    hi/lo in registers (truncating split; residual term ~2^-16 rel).
//    Removes 32 barrier drains/block; kernel = load -> split -> MFMA.
//  - softmax rows sum to 1 exactly => rowsum==1, dinv==rsqrt(2): rowsum
//    kernels deleted, deg division in score2 deleted (ref numeric deviation
//    ~1e-6, 4 orders below tolerance).
//  - scan_kernel also writes graph dinv; bn + 3 W-splits merged into one
//    prep kernel; aggregate/score edge loops 2-way unrolled (latency depth).
// Workspace map (MB), peak ~104:
//  [0,64)   XW fp32 (dead after aggregate) -> IND1 -> X2T split -> A3/ADJ2
//  [32,64)  BNH1 split -> H2T split
//  [64,96)  H1 fp32 -> ADJ1 split -> X3T split + H3 fp32
//  [96,~104) CSR + degree arrays + misc persistent
// ---------------------------------------------------------------------------

#define B_   128
#define N_   512
#define NN_  65536
#define E_   1048576
#define LAMB_ 1.0f
#define RSQRT2_ 0.70710678118654752f

typedef unsigned short ushort_t;
typedef __attribute__((ext_vector_type(8))) short bf16x8;
typedef __attribute__((ext_vector_type(8))) unsigned short u16x8;
typedef __attribute__((ext_vector_type(4))) float f32x4;

__device__ inline float waveReduceSum(float v) {
    #pragma unroll
    for (int o = 32; o > 0; o >>= 1) v += __shfl_down(v, o, 64);
    return v;
}
__device__ inline ushort_t f2bf(float f) {
    unsigned u = __float_as_uint(f);
    u += 0x7fffu + ((u >> 16) & 1u);
    return (ushort_t)(u >> 16);
}
__device__ inline void split2(float f, ushort_t& h, ushort_t& l) {
    h = f2bf(f);
    float r = f - __uint_as_float((unsigned)h << 16);
    l = f2bf(r);
}
__device__ inline float bfu(ushort_t s) { return __uint_as_float((unsigned)s << 16); }
__device__ inline bf16x8 as_bf(u16x8 u) { union { u16x8 a; bf16x8 b; } c; c.a = u; return c.b; }

// store 4 values (consecutive rows) into transposed split arrays at base
__device__ inline void store_T4(ushort_t* __restrict__ Th, ushort_t* __restrict__ Tl,
                                size_t base, const float* v) {
    ushort_t h[4], l[4];
    #pragma unroll
    for (int r = 0; r < 4; r++) split2(v[r], h[r], l[r]);
    uint2 ph = make_uint2((unsigned)h[0] | ((unsigned)h[1] << 16),
                          (unsigned)h[2] | ((unsigned)h[3] << 16));
    uint2 pl = make_uint2((unsigned)l[0] | ((unsigned)l[1] << 16),
                          (unsigned)l[2] | ((unsigned)l[3] << 16));
    *(uint2*)&Th[base] = ph;
    *(uint2*)&Tl[base] = pl;
}
__device__ inline void load_T4(const ushort_t* __restrict__ Th, const ushort_t* __restrict__ Tl,
                               size_t base, float* v) {
    uint2 ph = *(const uint2*)&Th[base];
    uint2 pl = *(const uint2*)&Tl[base];
    v[0] = __uint_as_float(ph.x << 16) + __uint_as_float(pl.x << 16);
    v[1] = __uint_as_float(ph.x & 0xffff0000u) + __uint_as_float(pl.x & 0xffff0000u);
    v[2] = __uint_as_float(ph.y << 16) + __uint_as_float(pl.y << 16);
    v[3] = __uint_as_float(ph.y & 0xffff0000u) + __uint_as_float(pl.y & 0xffff0000u);
}

// ---------------- pure split-bf16 MFMA core: C(128x128)=A[M][K]@B^T[N][K] ---
template<int KSTEPS>
__device__ __attribute__((always_inline)) void mfma_core(
    const ushort_t* __restrict__ Ah, const ushort_t* __restrict__ Al, int lda,
    const ushort_t* __restrict__ Bh, const ushort_t* __restrict__ Bl, int ldb,
    int rowbase, int colbase, int fl, int fh, f32x4 acc[4][4]) {
    #pragma unroll
    for (int ks = 0; ks < KSTEPS; ks++) {
        int kg = ks * 32 + fh * 8;
        bf16x8 bh[4], bl[4];
        #pragma unroll
        for (int ni = 0; ni < 4; ni++) {
            size_t off = (size_t)(colbase + ni * 16 + fl) * ldb + kg;
            bh[ni] = *(const bf16x8*)&Bh[off];
            bl[ni] = *(const bf16x8*)&Bl[off];
        }
        #pragma unroll
        for (int mi = 0; mi < 4; mi++) {
            size_t off = (size_t)(rowbase + mi * 16 + fl) * lda + kg;
            bf16x8 ah = *(const bf16x8*)&Ah[off];
            bf16x8 al = *(const bf16x8*)&Al[off];
            #pragma unroll
            for (int ni = 0; ni < 4; ni++) {
                acc[mi][ni] = __builtin_amdgcn_mfma_f32_16x16x32_bf16(al, bh[ni], acc[mi][ni], 0, 0, 0);
                acc[mi][ni] = __builtin_amdgcn_mfma_f32_16x16x32_bf16(ah, bl[ni], acc[mi][ni], 0, 0, 0);
                acc[mi][ni] = __builtin_amdgcn_mfma_f32_16x16x32_bf16(ah, bh[ni], acc[mi][ni], 0, 0, 0);
            }
        }
    }
}

// ---------------- prep: W1/W2/W3 split+transpose + BN coefficients ----------
__global__ void prep_kernel(const float* __restrict__ W1, const float* __restrict__ W2,
                            const float* __restrict__ W3,
                            const float* __restrict__ g, const float* __restrict__ be,
                            const float* __restrict__ me, const float* __restrict__ va,
                            ushort_t* __restrict__ W1TH, ushort_t* __restrict__ W1TL,
                            ushort_t* __restrict__ W2TH, ushort_t* __restrict__ W2TL,
                            ushort_t* __restrict__ W3TH, ushort_t* __restrict__ W3TL,
                            float* __restrict__ sBN, float* __restrict__ tBN) {
    int bx = blockIdx.x, n = threadIdx.x;
    if (bx < 512) {
        float v = W1[bx * 256 + n];
        ushort_t h, l; split2(v, h, l);
        W1TH[n * 512 + bx] = h; W1TL[n * 512 + bx] = l;
    } else if (bx < 768) {
        int k = bx - 512;
        float v = W2[k * 256 + n];
        ushort_t h, l; split2(v, h, l);
        W2TH[n * 256 + k] = h; W2TL[n * 256 + k] = l;
    } else if (bx < 1024) {
        int k = bx - 768;
        float v = W3[k * 256 + n];
        ushort_t h, l; split2(v, h, l);
        W3TH[n * 256 + k] = h; W3TL[n * 256 + k] = l;
    } else {
        float s = g[n] * rsqrtf(va[n] + 1e-5f);
        sBN[n] = s;
        tBN[n] = be[n] - me[n] * s;
    }
}

// ---------------- barrier-free split-bf16 MFMA GEMM: XW = x @ W1 ------------
// 128x128 block = 4 waves of 64x64. Per K-step a lane loads its OWN A
// fragment (8 consecutive fp32 of one row, fh groups contiguous 128B/row),
// splits to bf16 hi/lo in registers. No LDS, no __syncthreads.
__global__ __launch_bounds__(256) void gemm_xw_mfma2(
    const float* __restrict__ A, const ushort_t* __restrict__ Bhi,
    const ushort_t* __restrict__ Blo, float* __restrict__ C) {
    int m0 = blockIdx.x * 128, n0 = blockIdx.y * 128;
    int lane = threadIdx.x & 63, w = threadIdx.x >> 6;
    int wm = (w & 1) * 64, wn = (w >> 1) * 64;
    int fl = lane & 15, fh = lane >> 4;
    f32x4 acc[4][4] = {};
    const float*    Ab  = A   + (size_t)(m0 + wm + fl) * 512 + fh * 8;
    const ushort_t* Bhb = Bhi + (size_t)(n0 + wn + fl) * 512 + fh * 8;
    const ushort_t* Blb = Blo + (size_t)(n0 + wn + fl) * 512 + fh * 8;
    #pragma unroll 2
    for (int ks = 0; ks < 16; ks++) {
        int kg = ks * 32;
        bf16x8 bh[4], bl[4];
        #pragma unroll
        for (int ni = 0; ni < 4; ni++) {
            size_t off = (size_t)ni * (16 * 512) + kg;
            bh[ni] = *(const bf16x8*)&Bhb[off];
            bl[ni] = *(const bf16x8*)&Blb[off];
        }
        #pragma unroll
        for (int mi = 0; mi < 4; mi++) {
            const float* ap = Ab + (size_t)mi * (16 * 512) + kg;
            float4 q0 = *(const float4*)ap;
            float4 q1 = *(const float4*)(ap + 4);
            float f[8] = {q0.x, q0.y, q0.z, q0.w, q1.x, q1.y, q1.z, q1.w};
            u16x8 uh, ul;
            #pragma unroll
            for (int i = 0; i < 8; i++) {
                unsigned u = __float_as_uint(f[i]);
                uh[i] = (ushort_t)(u >> 16);                       // trunc hi
                float lf = f[i] - __uint_as_float(u & 0xffff0000u);
                ul[i] = (ushort_t)(__float_as_uint(lf) >> 16);     // trunc lo
            }
            bf16x8 ah = as_bf(uh), al = as_bf(ul);
            #pragma unroll
            for (int ni = 0; ni < 4; ni++) {
                acc[mi][ni] = __builtin_amdgcn_mfma_f32_16x16x32_bf16(al, bh[ni], acc[mi][ni], 0, 0, 0);
                acc[mi][ni] = __builtin_amdgcn_mfma_f32_16x16x32_bf16(ah, bl[ni], acc[mi][ni], 0, 0, 0);
                acc[mi][ni] = __builtin_amdgcn_mfma_f32_16x16x32_bf16(ah, bh[ni], acc[mi][ni], 0, 0, 0);
            }
        }
    }
    #pragma unroll
    for (int mi = 0; mi < 4; mi++)
        #pragma unroll
        for (int ni = 0; ni < 4; ni++)
            #pragma unroll
            for (int r = 0; r < 4; r++)
                C[(size_t)(m0 + wm + mi * 16 + fh * 4 + r) * 256 + n0 + wn + ni * 16 + fl]
                    = acc[mi][ni][r];
}

// ---------------- CSR build -------------------------------------------------
__global__ void count_kernel(const int* __restrict__ dst, int* __restrict__ indeg) {
    int e = blockIdx.x * 256 + threadIdx.x;
    if (e < E_) atomicAdd(&indeg[dst[e] & 65535], 1);
}
__global__ void scan_kernel(const int* __restrict__ indeg, int* __restrict__ rowstart,
                            int* __restrict__ cursor, float* __restrict__ dinv) {
    __shared__ int part[1024];
    int t = threadIdx.x;
    int base = t * 64;
    int s = 0;
    for (int i = 0; i < 64; i++) s += indeg[base + i];
    part[t] = s;
    __syncthreads();
    for (int off = 1; off < 1024; off <<= 1) {
        int v = (t >= off) ? part[t - off] : 0;
        __syncthreads();
        part[t] += v;
        __syncthreads();
    }
    int run = (t == 0) ? 0 : part[t - 1];
    for (int i = 0; i < 64; i++) {
        int dg = indeg[base + i];
        rowstart[base + i] = run;
        cursor[base + i] = run;
        dinv[base + i] = rsqrtf((float)dg + 1.0f);
        run += dg;
    }
}
__global__ void scatter_csr_kernel(const int* __restrict__ src, const int* __restrict__ dst,
                                   int* __restrict__ cursor, int* __restrict__ csr) {
    int e = blockIdx.x * 256 + threadIdx.x;
    if (e < E_) {
        int pos = atomicAdd(&cursor[dst[e] & 65535], 1);
        csr[pos & (E_ - 1)] = src[e] & 65535;
    }
}

// ---------------- sparse GCN aggregate (2-way unrolled edge loop) -----------
__global__ void aggregate_kernel(const float4* __restrict__ xw, const int* __restrict__ rowstart,
                                 const int* __restrict__ indeg, const float* __restrict__ dinv,
                                 const int* __restrict__ csr, const float* __restrict__ b1,
                                 float4* __restrict__ hout) {
    int bid = (blockIdx.x & 7) * 2048 + (blockIdx.x >> 3);
    int node = bid * 4 + (threadIdx.x >> 6);
    int lane = threadIdx.x & 63;
    int beg = rowstart[node], cnt = indeg[node];
    float di = dinv[node];
    float4 acc = make_float4(0.f, 0.f, 0.f, 0.f);
    int t = 0;
    for (; t + 1 < cnt; t += 2) {
        int s0 = csr[(beg + t) & (E_ - 1)] & 65535;
        int s1 = csr[(beg + t + 1) & (E_ - 1)] & 65535;
        float w0 = dinv[s0] * di, w1 = dinv[s1] * di;
        float4 v0 = xw[(size_t)s0 * 64 + lane];
        float4 v1 = xw[(size_t)s1 * 64 + lane];
        acc.x += v0.x * w0 + v1.x * w1;
        acc.y += v0.y * w0 + v1.y * w1;
        acc.z += v0.z * w0 + v1.z * w1;
        acc.w += v0.w * w0 + v1.w * w1;
    }
    if (t < cnt) {
        int s0 = csr[(beg + t) & (E_ - 1)] & 65535;
        float w0 = dinv[s0] * di;
        float4 v0 = xw[(size_t)s0 * 64 + lane];
        acc.x += v0.x * w0; acc.y += v0.y * w0; acc.z += v0.z * w0; acc.w += v0.w * w0;
    }
    {
        float w0 = di * di;
        float4 v = xw[(size_t)node * 64 + lane];
        acc.x += v.x * w0; acc.y += v.y * w0; acc.z += v.z * w0; acc.w += v.w * w0;
    }
    int c4 = lane * 4;
    acc.x = fmaxf(acc.x + b1[c4 + 0], 0.f);
    acc.y = fmaxf(acc.y + b1[c4 + 1], 0.f);
    acc.z = fmaxf(acc.z + b1[c4 + 2], 0.f);
    acc.w = fmaxf(acc.w + b1[c4 + 3], 0.f);
    hout[(size_t)node * 64 + lane] = acc;
}

// ---------------- pool_sparse score (2-way unrolled) ------------------------
__global__ void score_kernel(const float4* __restrict__ h, const int* __restrict__ rowstart,
                             const int* __restrict__ indeg, const int* __restrict__ csr,
                             float* __restrict__ score) {
    int bid = (blockIdx.x & 7) * 2048 + (blockIdx.x >> 3);
    int node = bid * 4 + (threadIdx.x >> 6);
    int lane = threadIdx.x & 63;
    int beg = rowstart[node], cnt = indeg[node];
    float degp = fmaxf((float)cnt, 1.0f);
    float4 nb = make_float4(0.f, 0.f, 0.f, 0.f);
    int t = 0;
    for (; t + 1 < cnt; t += 2) {
        int s0 = csr[(beg + t) & (E_ - 1)] & 65535;
        int s1 = csr[(beg + t + 1) & (E_ - 1)] & 65535;
        float4 v0 = h[(size_t)s0 * 64 + lane];
        float4 v1 = h[(size_t)s1 * 64 + lane];
        nb.x += v0.x + v1.x; nb.y += v0.y + v1.y;
        nb.z += v0.z + v1.z; nb.w += v0.w + v1.w;
    }
    if (t < cnt) {
        int s0 = csr[(beg + t) & (E_ - 1)] & 65535;
        float4 v0 = h[(size_t)s0 * 64 + lane];
        nb.x += v0.x; nb.y += v0.y; nb.z += v0.z; nb.w += v0.w;
    }
    float4 x = h[(size_t)node * 64 + lane];
    float p = fabsf(x.x - nb.x / degp) + fabsf(x.y - nb.y / degp) +
              fabsf(x.z - nb.z / degp) + fabsf(x.w - nb.w / degp);
    p = waveReduceSum(p);
    if (lane == 0) score[node] = p;
}

// ---------------- bitonic top-k ---------------------------------------------
__global__ void topk_kernel(const float* __restrict__ score, int n, int k,
                            int* __restrict__ out_local, int* __restrict__ rank, int Nfull) {
    int b = blockIdx.x, i = threadIdx.x;
    __shared__ float ss[512];
    __shared__ int si[512];
    ss[i] = score[b * n + i];
    si[i] = i;
    __syncthreads();
    for (int kk = 2; kk <= n; kk <<= 1)
        for (int j = kk >> 1; j > 0; j >>= 1) {
            int l = i ^ j;
            if (l > i) {
                float s1 = ss[i], s2 = ss[l];
                int i1 = si[i], i2 = si[l];
                bool up = ((i & kk) == 0);
                bool before = (s1 > s2) || (s1 == s2 && i1 < i2);
                bool doswap = up ? (!before) : before;
                if (doswap) { ss[i] = s2; ss[l] = s1; si[i] = i2; si[l] = i1; }
            }
            __syncthreads();
        }
    if (i < k) {
        int loc = si[i];
        out_local[b * k + i] = loc;
        if (rank) rank[b * Nfull + loc] = i;
    }
}

// ---------------- gather + BN + split (pool-1) ------------------------------
__global__ void gather_bn_kernel(const float4* __restrict__ src, const int* __restrict__ idxl,
                                 const float* __restrict__ sBN, const float* __restrict__ tBN,
                                 float4* __restrict__ H1, ushort_t* __restrict__ BNh,
                                 ushort_t* __restrict__ BNl) {
    int row = blockIdx.x;      // B*256
    int b = row >> 8;
    int node = b * 512 + (idxl[row] & 511);
    int lane = threadIdx.x;    // 64
    float4 v = src[(size_t)node * 64 + lane];
    H1[(size_t)row * 64 + lane] = v;
    int c0 = lane * 4;
    float bn[4];
    bn[0] = v.x * sBN[c0 + 0] + tBN[c0 + 0];
    bn[1] = v.y * sBN[c0 + 1] + tBN[c0 + 1];
    bn[2] = v.z * sBN[c0 + 2] + tBN[c0 + 2];
    bn[3] = v.w * sBN[c0 + 3] + tBN[c0 + 3];
    ushort_t h[4], l[4];
    #pragma unroll
    for (int j = 0; j < 4; j++) split2(bn[j], h[j], l[j]);
    uint2 ph = make_uint2((unsigned)h[0] | ((unsigned)h[1] << 16),
                          (unsigned)h[2] | ((unsigned)h[3] << 16));
    uint2 pl = make_uint2((unsigned)l[0] | ((unsigned)l[1] << 16),
                          (unsigned)l[2] | ((unsigned)l[3] << 16));
    *(uint2*)&BNh[(size_t)row * 256 + c0] = ph;
    *(uint2*)&BNl[(size_t)row * 256 + c0] = pl;
}

// ---------------- readouts / e-f dots ---------------------------------------
__global__ void readout_kernel(const float* __restrict__ x, int k, float* __restrict__ out) {
    int b = blockIdx.x, q = blockIdx.y, c = threadIdx.x;
    int chunk = k >> 2;
    int j0 = q * chunk;
    float mx = 0.f, sm = 0.f;
    for (int j = j0; j < j0 + chunk; j++) {
        float v = x[((size_t)(b * k + j)) * 256 + c];
        mx = fmaxf(mx, v);
        sm += v;
    }
    atomicMax((unsigned int*)&out[b * 512 + c], __float_as_uint(mx));
    atomicAdd(&out[b * 512 + 256 + c], sm * (1.0f / (float)k));
}
__global__ void readout_split_kernel(const ushort_t* __restrict__ Ah,
                                     const ushort_t* __restrict__ Al,
                                     int k, float* __restrict__ out) {
    int b = blockIdx.x, q = blockIdx.y, c = threadIdx.x;
    int chunk = k >> 2;
    int j0 = q * chunk;
    float mx = 0.f, sm = 0.f;
    for (int j = j0; j < j0 + chunk; j++) {
        size_t idx = ((size_t)(b * k + j)) * 256 + c;
        float v = bfu(Ah[idx]) + bfu(Al[idx]);
        mx = fmaxf(mx, v);
        sm += v;
    }
    atomicMax((unsigned int*)&out[b * 512 + c], __float_as_uint(mx));
    atomicAdd(&out[b * 512 + 256 + c], sm * (1.0f / (float)k));
}
__global__ void ef_plain_kernel(const float4* __restrict__ x, const float* __restrict__ att,
                                float* __restrict__ e, float* __restrict__ f) {
    int row = blockIdx.x * 4 + (threadIdx.x >> 6);
    int lane = threadIdx.x & 63;
    float4 v = x[(size_t)row * 64 + lane];
    const float* ap = att + lane * 8;
    float es = v.x * ap[0] + v.y * ap[2] + v.z * ap[4] + v.w * ap[6];
    float fs = v.x * ap[1] + v.y * ap[3] + v.z * ap[5] + v.w * ap[7];
    es = waveReduceSum(es);
    fs = waveReduceSum(fs);
    if (lane == 0) { e[row] = es; f[row] = fs; }
}
__global__ void ef_split_kernel(const ushort_t* __restrict__ Ah, const ushort_t* __restrict__ Al,
                                const float* __restrict__ att,
                                float* __restrict__ e, float* __restrict__ f) {
    int row = blockIdx.x * 4 + (threadIdx.x >> 6);
    int lane = threadIdx.x & 63;
    size_t base = (size_t)row * 256 + lane * 4;
    float v[4];
    load_T4(Ah, Al, base, v);
    const float* ap = att + lane * 8;
    float es = v[0] * ap[0] + v[1] * ap[2] + v[2] * ap[4] + v[3] * ap[6];
    float fs = v[0] * ap[1] + v[1] * ap[3] + v[2] * ap[5] + v[3] * ap[7];
    es = waveReduceSum(es);
    fs = waveReduceSum(fs);
    if (lane == 0) { e[row] = es; f[row] = fs; }
}

// ---------------- A_ind scatter / softmax-split -----------------------------
__global__ void scatter_A_kernel(const int* __restrict__ src, const int* __restrict__ dst,
                                 const int* __restrict__ rank, float* __restrict__ adj1) {
    int e = blockIdx.x * 256 + threadIdx.x;
    if (e >= E_) return;
    int s = src[e] & 65535, d = dst[e] & 65535;
    int ns = rank[s], nd = rank[d];
    if ((unsigned)ns < 256u && (unsigned)nd < 256u) {
        int g = s >> 9;
        adj1[(size_t)g * 65536 + ns * 256 + nd] = 1.0f;
    }
}
__global__ void softmax_split_kernel(const float* __restrict__ ind, const float* __restrict__ e,
                                     const float* __restrict__ f, int k,
                                     ushort_t* __restrict__ oh, ushort_t* __restrict__ ol) {
    int row = blockIdx.x;
    int b = row / k;
    int c = threadIdx.x;
    __shared__ float red[256];
    float v = ind[(size_t)row * k + c];
    float lg = e[row] + f[b * k + c] + LAMB_ * v;
    red[c] = lg;
    __syncthreads();
    for (int s = k >> 1; s > 0; s >>= 1) {
        if (c < s) red[c] = fmaxf(red[c], red[c + s]);
        __syncthreads();
    }
    float mx = red[0];
    __syncthreads();
    float ex = expf(lg - mx);
    red[c] = ex;
    __syncthreads();
    for (int s = k >> 1; s > 0; s >>= 1) {
        if (c < s) red[c] += red[c + s];
        __syncthreads();
    }
    float p = ex / red[0];
    ushort_t h, l;
    split2(p, h, l);
    oh[(size_t)row * k + c] = h;
    ol[(size_t)row * k + c] = l;
}
__global__ void gather_adj2_split_kernel(const ushort_t* __restrict__ Ah,
                                         const ushort_t* __restrict__ Al,
                                         const int* __restrict__ idx2,
                                         float* __restrict__ adj2) {
    int ii = blockIdx.x, b = blockIdx.y, jj = threadIdx.x;
    int ri = idx2[b * 128 + ii] & 255, rj = idx2[b * 128 + jj] & 255;
    size_t idx = (size_t)b * 65536 + ri * 256 + rj;
    adj2[((size_t)(b * 128 + ii)) * 128 + jj] = bfu(Ah[idx]) + bfu(Al[idx]);
}

// ---------------- A3 = H2 rows (idx2) in split normal layout ----------------
__global__ void gather_a3_kernel(const ushort_t* __restrict__ H2Th,
                                 const ushort_t* __restrict__ H2Tl,
                                 const int* __restrict__ idx2,
                                 ushort_t* __restrict__ A3h, ushort_t* __restrict__ A3l) {
    int row = blockIdx.x;     // B*128
    int b = row >> 7;
    int node = idx2[row] & 255;
    int lane = threadIdx.x;   // 64
    int c0 = lane * 4;
    unsigned h[4], l[4];
    #pragma unroll
    for (int j = 0; j < 4; j++) {
        size_t idx = ((size_t)(b * 256 + c0 + j)) * 256 + node;
        h[j] = H2Th[idx];
        l[j] = H2Tl[idx];
    }
    uint2 ph = make_uint2(h[0] | (h[1] << 16), h[2] | (h[3] << 16));
    uint2 pl = make_uint2(l[0] | (l[1] << 16), l[2] | (l[3] << 16));
    *(uint2*)&A3h[(size_t)row * 256 + c0] = ph;
    *(uint2*)&A3l[(size_t)row * 256 + c0] = pl;
}

// ---------------- batched MFMA GEMMs (dinv == rsqrt(2) constants) -----------
// (a) X2T = (rsqrt2 * (BN(H1) @ W2))^T, stored split [n][m]
__global__ __launch_bounds__(256) void gemm_x2_mfma(
    const ushort_t* __restrict__ Ah, const ushort_t* __restrict__ Al,
    const ushort_t* __restrict__ Bh, const ushort_t* __restrict__ Bl,
    ushort_t* __restrict__ XTh, ushort_t* __restrict__ XTl) {
    int b = blockIdx.z;
    int m0 = blockIdx.x * 128, n0 = blockIdx.y * 128;
    int lane = threadIdx.x & 63, w = threadIdx.x >> 6;
    int wm = (w & 1) * 64, wn = (w >> 1) * 64;
    int fl = lane & 15, fh = lane >> 4;
    f32x4 acc[4][4] = {};
    mfma_core<8>(Ah + (size_t)b * 65536, Al + (size_t)b * 65536, 256,
                 Bh, Bl, 256, m0 + wm, n0 + wn, fl, fh, acc);
    #pragma unroll
    for (int mi = 0; mi < 4; mi++) {
        int row0 = m0 + wm + mi * 16 + fh * 4;
        #pragma unroll
        for (int ni = 0; ni < 4; ni++) {
            int col = n0 + wn + ni * 16 + fl;
            float v[4];
            #pragma unroll
            for (int r = 0; r < 4; r++) v[r] = acc[mi][ni][r] * RSQRT2_;
            store_T4(XTh, XTl, ((size_t)(b * 256 + col)) * 256 + row0, v);
        }
    }
}

// (b) H2T = relu(rsqrt2*(ADJ1@X2 + X2_i) + b2)^T, stored split [n][m]
__global__ __launch_bounds__(256) void gemm_h2_mfma(
    const ushort_t* __restrict__ Ah, const ushort_t* __restrict__ Al,
    const ushort_t* __restrict__ Xh, const ushort_t* __restrict__ Xl,
    const float* __restrict__ b2,
    ushort_t* __restrict__ Hh, ushort_t* __restrict__ Hl) {
    int b = blockIdx.z;
    int m0 = blockIdx.x * 128, n0 = blockIdx.y * 128;
    int lane = threadIdx.x & 63, w = threadIdx.x >> 6;
    int wm = (w & 1) * 64, wn = (w >> 1) * 64;
    int fl = lane & 15, fh = lane >> 4;
    f32x4 acc[4][4] = {};
    mfma_core<8>(Ah + (size_t)b * 65536, Al + (size_t)b * 65536, 256,
                 Xh + (size_t)b * 65536, Xl + (size_t)b * 65536, 256,
                 m0 + wm, n0 + wn, fl, fh, acc);
    #pragma unroll
    for (int mi = 0; mi < 4; mi++) {
        int row0 = m0 + wm + mi * 16 + fh * 4;
        #pragma unroll
        for (int ni = 0; ni < 4; ni++) {
            int col = n0 + wn + ni * 16 + fl;
            size_t baseT = ((size_t)(b * 256 + col)) * 256 + row0;
            float xv[4], v[4];
            load_T4(Xh, Xl, baseT, xv);
            float bc = b2[col];
            #pragma unroll
            for (int r = 0; r < 4; r++)
                v[r] = fmaxf((acc[mi][ni][r] + xv[r]) * RSQRT2_ + bc, 0.f);
            store_T4(Hh, Hl, baseT, v);
        }
    }
}

// (c) score2 += sum_cols |H2 - ADJ1@H2|   (deg == 1)
__global__ __launch_bounds__(256) void gemm_score_mfma(
    const ushort_t* __restrict__ Ah, const ushort_t* __restrict__ Al,
    const ushort_t* __restrict__ Hh, const ushort_t* __restrict__ Hl,
    float* __restrict__ score2) {
    int b = blockIdx.z;
    int m0 = blockIdx.x * 128, n0 = blockIdx.y * 128;
    int lane = threadIdx.x & 63, w = threadIdx.x >> 6;
    int wm = (w & 1) * 64, wn = (w >> 1) * 64;
    int fl = lane & 15, fh = lane >> 4;
    f32x4 acc[4][4] = {};
    mfma_core<8>(Ah + (size_t)b * 65536, Al + (size_t)b * 65536, 256,
                 Hh + (size_t)b * 65536, Hl + (size_t)b * 65536, 256,
                 m0 + wm, n0 + wn, fl, fh, acc);
    float part[4][4];
    #pragma unroll
    for (int mi = 0; mi < 4; mi++)
        #pragma unroll
        for (int r = 0; r < 4; r++) part[mi][r] = 0.f;
    #pragma unroll
    for (int mi = 0; mi < 4; mi++) {
        int row0 = m0 + wm + mi * 16 + fh * 4;
        #pragma unroll
        for (int ni = 0; ni < 4; ni++) {
            int col = n0 + wn + ni * 16 + fl;
            size_t baseT = ((size_t)(b * 256 + col)) * 256 + row0;
            float hv[4];
            load_T4(Hh, Hl, baseT, hv);
            #pragma unroll
            for (int r = 0; r < 4; r++)
                part[mi][r] += fabsf(hv[r] - acc[mi][ni][r]);
        }
    }
    #pragma unroll
    for (int mi = 0; mi < 4; mi++) {
        int row0 = m0 + wm + mi * 16 + fh * 4;
        #pragma unroll
        for (int r = 0; r < 4; r++) {
            float s = part[mi][r];
            #pragma unroll
            for (int o = 8; o >= 1; o >>= 1) s += __shfl_xor(s, o, 64);
            if (fl == 0) atomicAdd(&score2[b * 256 + row0 + r], s);
        }
    }
}

// (d) X3T = (rsqrt2 * (A3 @ W3))^T, stored split [n=256][m=128]
__global__ __launch_bounds__(256) void gemm_x3_mfma(
    const ushort_t* __restrict__ Ah, const ushort_t* __restrict__ Al,
    const ushort_t* __restrict__ Bh, const ushort_t* __restrict__ Bl,
    ushort_t* __restrict__ XTh, ushort_t* __restrict__ XTl) {
    int b = blockIdx.z;
    int m0 = blockIdx.x * 128, n0 = blockIdx.y * 128;
    int lane = threadIdx.x & 63, w = threadIdx.x >> 6;
    int wm = (w & 1) * 64, wn = (w >> 1) * 64;
    int fl = lane & 15, fh = lane >> 4;
    f32x4 acc[4][4] = {};
    mfma_core<8>(Ah + (size_t)b * 32768, Al + (size_t)b * 32768, 256,
                 Bh, Bl, 256, m0 + wm, n0 + wn, fl, fh, acc);
    #pragma unroll
    for (int mi = 0; mi < 4; mi++) {
        int row0 = m0 + wm + mi * 16 + fh * 4;
        #pragma unroll
        for (int ni = 0; ni < 4; ni++) {
            int col = n0 + wn + ni * 16 + fl;
            float v[4];
            #pragma unroll
            for (int r = 0; r < 4; r++) v[r] = acc[mi][ni][r] * RSQRT2_;
            store_T4(XTh, XTl, ((size_t)(b * 256 + col)) * 128 + row0, v);
        }
    }
}

// (e) H3 = relu(rsqrt2*(ADJ2@X3 + X3_i) + b3), fp32 normal layout
__global__ __launch_bounds__(256) void gemm_h3_mfma(
    const ushort_t* __restrict__ Ah, const ushort_t* __restrict__ Al,
    const ushort_t* __restrict__ Xh, const ushort_t* __restrict__ Xl,
    const float* __restrict__ b3,
    float* __restrict__ H3) {
    int b = blockIdx.z;
    int m0 = blockIdx.x * 128, n0 = blockIdx.y * 128;
    int lane = threadIdx.x & 63, w = threadIdx.x >> 6;
    int wm = (w & 1) * 64, wn = (w >> 1) * 64;
    int fl = lane & 15, fh = lane >> 4;
    f32x4 acc[4][4] = {};
    mfma_core<4>(Ah + (size_t)b * 16384, Al + (size_t)b * 16384, 128,
                 Xh + (size_t)b * 32768, Xl + (size_t)b * 32768, 128,
                 m0 + wm, n0 + wn, fl, fh, acc);
    #pragma unroll
    for (int mi = 0; mi < 4; mi++) {
        int row0 = m0 + wm + mi * 16 + fh * 4;
        #pragma unroll
        for (int ni = 0; ni < 4; ni++) {
            int col = n0 + wn + ni * 16 + fl;
            size_t baseT = ((size_t)(b * 256 + col)) * 128 + row0;
            float xv[4];
            load_T4(Xh, Xl, baseT, xv);
            float bc = b3[col];
            #pragma unroll
            for (int r = 0; r < 4; r++) {
                float v = fmaxf((acc[mi][ni][r] + xv[r]) * RSQRT2_ + bc, 0.f);
                H3[(size_t)b * 32768 + (size_t)(row0 + r) * 256 + col] = v;
            }
        }
    }
}

// ---------------- head MLP (f32 outputs) ------------------------------------
__global__ void head_kernel(const float* __restrict__ x1, const float* __restrict__ x2,
                            const float* __restrict__ x3,
                            const float* __restrict__ w1, const float* __restrict__ b1,
                            const float* __restrict__ w2, const float* __restrict__ b2,
                            const float* __restrict__ w3, const float* __restrict__ b3,
                            float* __restrict__ out_x, float* __restrict__ out_lp) {
    int b = blockIdx.x, t = threadIdx.x;
    __shared__ float g[512], g1[256], g2[128], lg[10];
    __shared__ float lse;
    for (int i = t; i < 512; i += 256)
        g[i] = fmaxf(x1[b * 512 + i], 0.f) + fmaxf(x2[b * 512 + i], 0.f) + fmaxf(x3[b * 512 + i], 0.f);
    __syncthreads();
    {
        float acc = b1[t];
        for (int kk = 0; kk < 512; kk++) acc += g[kk] * w1[kk * 256 + t];
        g1[t] = fmaxf(acc, 0.f);
    }
    __syncthreads();
    if (t < 128) {
        float acc = b2[t];
        for (int kk = 0; kk < 256; kk++) acc += g1[kk] * w2[kk * 128 + t];
        float r = fmaxf(acc, 0.f);
        g2[t] = r;
        out_x[b * 128 + t] = r;
    }
    __syncthreads();
    if (t < 10) {
        float acc = b3[t];
        for (int kk = 0; kk < 128; kk++) acc += g2[kk] * w3[kk * 10 + t];
        lg[t] = acc;
    }
    __syncthreads();
    if (t == 0) {
        float m = -1e30f;
        for (int i = 0; i < 10; i++) m = fmaxf(m, lg[i]);
        float s = 0.f;
        for (int i = 0; i < 10; i++) s += expf(lg[i] - m);
        lse = m + logf(s);
    }
    __syncthreads();
    if (t < 10) out_lp[b * 10 + t] = lg[t] - lse;
}

// ---------------------------------------------------------------------------
extern "C" void kernel_launch(void* const* d_in, const int* in_sizes, int n_in,
                              void* d_out, int out_size, void* d_ws, size_t ws_size,
                              hipStream_t stream) {
    const float* X    = (const float*)d_in[0];
    const int*   EI   = (const int*)d_in[1];
    const float* W1   = (const float*)d_in[3];
    const float* B1v  = (const float*)d_in[4];
    const float* W2   = (const float*)d_in[5];
    const float* B2v  = (const float*)d_in[6];
    const float* W3   = (const float*)d_in[7];
    const float* B3v  = (const float*)d_in[8];
    const float* ATT1 = (const float*)d_in[9];
    const float* ATT2 = (const float*)d_in[10];
    const float* GAM  = (const float*)d_in[11];
    const float* BET  = (const float*)d_in[12];
    const float* MEA  = (const float*)d_in[13];
    const float* VAR  = (const float*)d_in[14];
    const float* L1W  = (const float*)d_in[15];
    const float* L1B  = (const float*)d_in[16];
    const float* L2W  = (const float*)d_in[17];
    const float* L2B  = (const float*)d_in[18];
    const float* L3W  = (const float*)d_in[19];
    const float* L3B  = (const float*)d_in[20];
    float* OUT = (float*)d_out;                 // f32 outputs
    const int OFF_LOGP = 16384, OFF_XU = 17664;

    const int* src = EI;
    const int* dst = EI + E_;

    uint8_t* w = (uint8_t*)d_ws;
    const size_t MB = 1u << 20;
    // region [0,64): XW -> IND1 -> X2T -> {A3, ADJ2IND, ADJ2 split}
    float*    XWp     = (float*)(w + 0);
    float*    IND1    = (float*)(w + 0);
    ushort_t* X2TH    = (ushort_t*)(w + 0);
    ushort_t* X2TL    = (ushort_t*)(w + 16 * MB);
    ushort_t* A3H     = (ushort_t*)(w + 0);
    ushort_t* A3L     = (ushort_t*)(w + 8 * MB);
    float*    ADJ2IND = (float*)(w + 16 * MB);
    ushort_t* ADJ2H   = (ushort_t*)(w + 24 * MB);
    ushort_t* ADJ2L   = (ushort_t*)(w + 28 * MB);
    // region [32,64): BNH1 split -> H2T split
    ushort_t* BNH1H   = (ushort_t*)(w + 32 * MB);
    ushort_t* BNH1L   = (ushort_t*)(w + 48 * MB);
    ushort_t* H2TH    = (ushort_t*)(w + 32 * MB);
    ushort_t* H2TL    = (ushort_t*)(w + 48 * MB);
    // region [64,96): H1 fp32 -> ADJ1 split -> {X3T split, H3 fp32}
    float*    H1      = (float*)(w + 64 * MB);
    ushort_t* ADJ1H   = (ushort_t*)(w + 64 * MB);
    ushort_t* ADJ1L   = (ushort_t*)(w + 80 * MB);
    ushort_t* X3TH    = (ushort_t*)(w + 64 * MB);
    ushort_t* X3TL    = (ushort_t*)(w + 72 * MB);
    float*    H3      = (float*)(w + 80 * MB);
    // region [96,...): persistent misc
    int*   CSR    = (int*)(w + 96 * MB);                  // 4 MB
    int*   INDEG  = (int*)(w + 100 * MB);
    int*   RSTART = INDEG + 65536;
    int*   CURSOR = RSTART + 65536;
    float* DINV   = (float*)(CURSOR + 65536);
    float* SCORE  = (float*)(w + 101 * MB);               // 256 KB
    uint8_t* mp = w + 101 * MB + 256 * 1024;
    int*   RANK   = (int*)mp;   mp += 256 * 1024;
    int*   IDX1   = (int*)mp;   mp += 128 * 1024;
    int*   IDX2   = (int*)mp;   mp += 64 * 1024;
    float* E1     = (float*)mp; mp += 128 * 1024;
    float* F1     = (float*)mp; mp += 128 * 1024;
    float* E2     = (float*)mp; mp += 64 * 1024;
    float* F2     = (float*)mp; mp += 64 * 1024;
    float* SC2    = (float*)mp; mp += 128 * 1024;
    float* SBN    = (float*)mp; mp += 4 * 1024;
    float* TBN    = (float*)mp; mp += 4 * 1024;
    float* X1R    = (float*)mp; mp += 256 * 1024;
    float* X2R    = (float*)mp; mp += 256 * 1024;
    float* X3R    = (float*)mp; mp += 256 * 1024;
    ushort_t* W1TH = (ushort_t*)mp; mp += 256 * 1024;     // [256][512]
    ushort_t* W1TL = (ushort_t*)mp; mp += 256 * 1024;
    ushort_t* W2TH = (ushort_t*)mp; mp += 128 * 1024;     // [256][256]
    ushort_t* W2TL = (ushort_t*)mp; mp += 128 * 1024;
    ushort_t* W3TH = (ushort_t*)mp; mp += 128 * 1024;
    ushort_t* W3TL = (ushort_t*)mp; mp += 128 * 1024;

    float* Hout = OUT + OFF_XU;               // h lives in the x__ output region

    hipMemsetAsync(INDEG, 0, 256 * 1024, stream);
    hipMemsetAsync(RANK, 0xFF, 256 * 1024, stream);
    hipMemsetAsync(SC2, 0, 128 * 1024, stream);
    hipMemsetAsync(X1R, 0, 768 * 1024, stream);   // X1R..X3R zero for atomic readouts

    prep_kernel<<<1025, 256, 0, stream>>>(W1, W2, W3, GAM, BET, MEA, VAR,
                                          W1TH, W1TL, W2TH, W2TL, W3TH, W3TL, SBN, TBN);
    gemm_xw_mfma2<<<dim3(512, 2), 256, 0, stream>>>(X, W1TH, W1TL, XWp);
    count_kernel<<<4096, 256, 0, stream>>>(dst, INDEG);
    scan_kernel<<<1, 1024, 0, stream>>>(INDEG, RSTART, CURSOR, DINV);
    scatter_csr_kernel<<<4096, 256, 0, stream>>>(src, dst, CURSOR, CSR);
    aggregate_kernel<<<16384, 256, 0, stream>>>((const float4*)XWp, RSTART, INDEG, DINV,
                                                CSR, B1v, (float4*)Hout);
    score_kernel<<<16384, 256, 0, stream>>>((const float4*)Hout, RSTART, INDEG, CSR, SCORE);
    topk_kernel<<<128, 512, 0, stream>>>(SCORE, 512, 256, IDX1, RANK, 512);
    gather_bn_kernel<<<32768, 64, 0, stream>>>((const float4*)Hout, IDX1, SBN, TBN,
                                               (float4*)H1, BNH1H, BNH1L);
    readout_kernel<<<dim3(128, 4), 256, 0, stream>>>(H1, 256, X1R);
    ef_plain_kernel<<<8192, 256, 0, stream>>>((const float4*)H1, ATT1, E1, F1);
    hipMemsetAsync(IND1, 0, (size_t)32 * MB, stream);     // XW dead (post-aggregate)
    scatter_A_kernel<<<4096, 256, 0, stream>>>(src, dst, RANK, IND1);
    softmax_split_kernel<<<32768, 256, 0, stream>>>(IND1, E1, F1, 256, ADJ1H, ADJ1L);
    gemm_x2_mfma<<<dim3(2, 2, 128), 256, 0, stream>>>(BNH1H, BNH1L, W2TH, W2TL,
                                                      X2TH, X2TL);
    gemm_h2_mfma<<<dim3(2, 2, 128), 256, 0, stream>>>(ADJ1H, ADJ1L, X2TH, X2TL, B2v,
                                                      H2TH, H2TL);
    gemm_score_mfma<<<dim3(2, 2, 128), 256, 0, stream>>>(ADJ1H, ADJ1L, H2TH, H2TL, SC2);
    topk_kernel<<<128, 256, 0, stream>>>(SC2, 256, 128, IDX2, nullptr, 0);
    gather_a3_kernel<<<16384, 64, 0, stream>>>(H2TH, H2TL, IDX2, A3H, A3L);
    readout_split_kernel<<<dim3(128, 4), 256, 0, stream>>>(A3H, A3L, 128, X2R);
    ef_split_kernel<<<4096, 256, 0, stream>>>(A3H, A3L, ATT2, E2, F2);
    gather_adj2_split_kernel<<<dim3(128, 128), 128, 0, stream>>>(ADJ1H, ADJ1L, IDX2, ADJ2IND);
    softmax_split_kernel<<<16384, 128, 0, stream>>>(ADJ2IND, E2, F2, 128, ADJ2H, ADJ2L);
    gemm_x3_mfma<<<dim3(1, 2, 128), 256, 0, stream>>>(A3H, A3L, W3TH, W3TL, X3TH, X3TL);
    gemm_h3_mfma<<<dim3(1, 2, 128), 256, 0, stream>>>(ADJ2H, ADJ2L, X3TH, X3TL, B3v, H3);
    readout_kernel<<<dim3(128, 4), 256, 0, stream>>>(H3, 128, X3R);
    head_kernel<<<128, 256, 0, stream>>>(X1R, X2R, X3R, L1W, L1B, L2W, L2B, L3W, L3B,
                                         OUT, OUT + OFF_LOGP);
}